// Round 1
// baseline (1049.935 us; speedup 1.0000x reference)
//
#include <hip/hip_runtime.h>
#include <hip/hip_bf16.h>

typedef __attribute__((ext_vector_type(8))) __bf16 bf16x8;
typedef __attribute__((ext_vector_type(4))) float f32x4;
typedef __hip_bfloat16 bf16;

#define SCALE_Q 0.17677669529663687f

// ---------------- weight fp32 -> bf16 ----------------
__global__ void cvt_kernel(const float* __restrict__ in, bf16* __restrict__ out, int n) {
  int i = blockIdx.x * 256 + threadIdx.x;
  if (i < n) out[i] = __float2bfloat16(in[i]);
}

// ---- LayerNorm (optionally fused shifted-window gather), fp32 in -> bf16 out ----
// One wave per token (192 channels = 3 floats/lane), 4 waves/block.
template<bool GATHER>
__global__ __launch_bounds__(256) void ln_kernel(const float* __restrict__ in,
                                                 const float* __restrict__ gw,
                                                 const float* __restrict__ gb,
                                                 bf16* __restrict__ out) {
  const int t = blockIdx.x * 4 + (threadIdx.x >> 6);
  const int lane = threadIdx.x & 63;
  long g;
  if (GATHER) {
    // windowed token t=(b_,n) reads x at rolled coords (+SHIFT mod 256)
    const int b_ = t >> 6, n = t & 63;
    const int b = b_ >> 10, wk = b_ & 1023, wi = wk >> 5, wj = wk & 31;
    const int i_ = n >> 3, j_ = n & 7;
    const int hf = (wi * 8 + i_ + 4) & 255, wf = (wj * 8 + j_ + 4) & 255;
    g = (((long)b * 256 + hf) * 256 + wf) * 192;
  } else {
    g = (long)t * 192;
  }
  const float x0 = in[g + lane], x1 = in[g + 64 + lane], x2 = in[g + 128 + lane];
  float s = x0 + x1 + x2;
  float s2 = x0 * x0 + x1 * x1 + x2 * x2;
  #pragma unroll
  for (int m = 1; m < 64; m <<= 1) { s += __shfl_xor(s, m); s2 += __shfl_xor(s2, m); }
  const float mu = s * (1.0f / 192.0f);
  const float rstd = rsqrtf(s2 * (1.0f / 192.0f) - mu * mu + 1e-5f);
  const long o = (long)t * 192;
  out[o + lane]       = __float2bfloat16((x0 - mu) * rstd * gw[lane]       + gb[lane]);
  out[o + 64 + lane]  = __float2bfloat16((x1 - mu) * rstd * gw[lane + 64]  + gb[lane + 64]);
  out[o + 128 + lane] = __float2bfloat16((x2 - mu) * rstd * gw[lane + 128] + gb[lane + 128]);
}

// ---------------- GEMM: C[m][n] = sum_k A[m][k] * W[n][k] (+bias), bf16 MFMA ----------------
// BM=128 BN=64 BK=64, 256 threads (4 waves, 2x2), XOR-swizzled LDS (16B chunks).
// EPI 0: qkv scatter (+q scale)   EPI 1: proj + window-reverse+roll + residual -> h_buf f32
// EPI 2: fc1 + exact gelu -> bf16 EPI 3: fc2 + h_buf residual -> f32 out
template<int EPI>
__global__ __launch_bounds__(256) void gemm_bt(const bf16* __restrict__ A,
                                               const bf16* __restrict__ Bw,
                                               const float* __restrict__ bias,
                                               int K, void* __restrict__ outp,
                                               const float* __restrict__ aux1,
                                               const float* __restrict__ aux2) {
  __shared__ __align__(16) bf16 Ald[128 * 64];
  __shared__ __align__(16) bf16 Bld[64 * 64];
  const int tid = threadIdx.x;
  const int n0 = blockIdx.x * 64;
  const long m0 = (long)blockIdx.y * 128;
  const int lane = tid & 63, wid = tid >> 6;
  const int wr = (wid >> 1) * 64, wc = (wid & 1) * 32;
  const int lg = lane >> 4, lr = lane & 15;

  f32x4 acc[4][2];
  #pragma unroll
  for (int i = 0; i < 4; i++)
    #pragma unroll
    for (int j = 0; j < 2; j++) acc[i][j] = (f32x4){0.f, 0.f, 0.f, 0.f};

  for (int k0 = 0; k0 < K; k0 += 64) {
    #pragma unroll
    for (int q = 0; q < 4; q++) {
      const int flat = q * 256 + tid, row = flat >> 3, c = flat & 7;
      const uint4 v = *(const uint4*)(A + (m0 + row) * K + k0 + c * 8);
      *(uint4*)((char*)Ald + row * 128 + ((c ^ (row & 7)) * 16)) = v;
    }
    #pragma unroll
    for (int q = 0; q < 2; q++) {
      const int flat = q * 256 + tid, row = flat >> 3, c = flat & 7;
      const uint4 v = *(const uint4*)(Bw + (n0 + row) * K + k0 + c * 8);
      *(uint4*)((char*)Bld + row * 128 + ((c ^ (row & 7)) * 16)) = v;
    }
    __syncthreads();
    #pragma unroll
    for (int ks = 0; ks < 2; ks++) {
      bf16x8 af[4], bfr[2];
      #pragma unroll
      for (int i = 0; i < 4; i++) {
        const int row = wr + i * 16 + lr;
        af[i] = *(const bf16x8*)((const char*)Ald + row * 128 + (((ks * 4 + lg) ^ (row & 7)) * 16));
      }
      #pragma unroll
      for (int j = 0; j < 2; j++) {
        const int row = wc + j * 16 + lr;
        bfr[j] = *(const bf16x8*)((const char*)Bld + row * 128 + (((ks * 4 + lg) ^ (row & 7)) * 16));
      }
      #pragma unroll
      for (int i = 0; i < 4; i++)
        #pragma unroll
        for (int j = 0; j < 2; j++)
          acc[i][j] = __builtin_amdgcn_mfma_f32_16x16x32_bf16(af[i], bfr[j], acc[i][j], 0, 0, 0);
    }
    __syncthreads();
  }

  #pragma unroll
  for (int i = 0; i < 4; i++) {
    #pragma unroll
    for (int j = 0; j < 2; j++) {
      #pragma unroll
      for (int r = 0; r < 4; r++) {
        const long m = m0 + wr + i * 16 + lg * 4 + r;   // token row
        const int cn = n0 + wc + j * 16 + lr;           // output col
        float v = acc[i][j][r] + bias[cn];
        if (EPI == 0) {
          const long b_ = m >> 6; const int n = (int)(m & 63);
          const int which = cn / 192, rem = cn - which * 192, head = rem >> 5, d = rem & 31;
          if (which == 0) v *= SCALE_Q;
          ((bf16*)outp)[((b_ * 6 + head) * 3 + which) * 2048 + n * 32 + d] = __float2bfloat16(v);
        } else if (EPI == 1) {
          const long b_ = m >> 6; const int n = (int)(m & 63);
          const int b = (int)(b_ >> 10), wk = (int)(b_ & 1023), wi = wk >> 5, wj = wk & 31;
          const int i_ = n >> 3, j_ = n & 7;
          const int hf = (wi * 8 + i_ + 4) & 255, wf = (wj * 8 + j_ + 4) & 255;
          const long g = (((long)b * 256 + hf) * 256 + wf) * 192 + cn;
          ((float*)outp)[g] = aux1[g] + v;   // h = shortcut + proj(attn)
        } else if (EPI == 2) {
          const float gv = 0.5f * v * (1.0f + erff(v * 0.70710678118654752f));
          ((bf16*)outp)[m * 768 + cn] = __float2bfloat16(gv);
        } else {
          ((float*)outp)[m * 192 + cn] = aux2[m * 192 + cn] + v;
        }
      }
    }
  }
}

// ---------------- windowed attention: one wave per (window, head) ----------------
__global__ __launch_bounds__(64) void attn_kernel(const bf16* __restrict__ qkv,
                                                  const float* __restrict__ rpb,
                                                  bf16* __restrict__ outp) {
  // smem: Q[64][40] @0 (5120B), K[64][40] @5120, Vt[32][72] @10240 (4608B)
  // P[64][72] (9216B) overlays Q+K after QK^T
  __shared__ __align__(16) char smem[14848];
  __shared__ float rps[225];
  const int bid = blockIdx.x;
  const int b_ = bid / 6, head = bid - b_ * 6;
  const int lane = threadIdx.x;
  const long base = ((long)b_ * 6 + head) * 3 * 2048;

  for (int t = lane; t < 225; t += 64) rps[t] = rpb[t * 6 + head];

  #pragma unroll
  for (int q = 0; q < 4; q++) {
    const int f = q * 64 + lane, row = f >> 2, c = f & 3;
    *(uint4*)(smem + row * 80 + c * 16) = *(const uint4*)(qkv + base + row * 32 + c * 8);
    *(uint4*)(smem + 5120 + row * 80 + c * 16) = *(const uint4*)(qkv + base + 2048 + row * 32 + c * 8);
  }
  {  // stage V transposed: Vt[d][m]
    const bf16* vsrc = qkv + base + 4096 + lane * 32;
    bf16 vv[32];
    #pragma unroll
    for (int q = 0; q < 4; q++) *(uint4*)&vv[q * 8] = *(const uint4*)(vsrc + q * 8);
    bf16* vt = (bf16*)(smem + 10240);
    #pragma unroll
    for (int d = 0; d < 32; d++) vt[d * 72 + lane] = vv[d];
  }
  __syncthreads();

  const int lg = lane >> 4, lr = lane & 15;
  const f32x4 z4 = {0.f, 0.f, 0.f, 0.f};
  f32x4 s[4][4];
  {  // S = Q K^T : K(dot)=32 = one MFMA step; 4x4 fragments of 16x16
    bf16x8 a[4], b[4];
    #pragma unroll
    for (int fi = 0; fi < 4; fi++)
      a[fi] = *(const bf16x8*)(smem + (fi * 16 + lr) * 80 + lg * 16);
    #pragma unroll
    for (int fj = 0; fj < 4; fj++)
      b[fj] = *(const bf16x8*)(smem + 5120 + (fj * 16 + lr) * 80 + lg * 16);
    #pragma unroll
    for (int fi = 0; fi < 4; fi++)
      #pragma unroll
      for (int fj = 0; fj < 4; fj++)
        s[fi][fj] = __builtin_amdgcn_mfma_f32_16x16x32_bf16(a[fi], b[fj], z4, 0, 0, 0);
  }

  // bias + shift-mask + row softmax; write P (bf16) to LDS
  const int wk = b_ & 1023; const int wi = wk >> 5, wj = wk & 31;
  const bool eh = (wi == 31), ew = (wj == 31);
  bf16* P = (bf16*)smem;
  #pragma unroll
  for (int fi = 0; fi < 4; fi++) {
    #pragma unroll
    for (int r = 0; r < 4; r++) {
      const int n = fi * 16 + lg * 4 + r;
      const int i1 = n >> 3, j1 = n & 7;
      const int labn = (eh ? (i1 < 4 ? 3 : 6) : 0) + (ew ? (j1 < 4 ? 1 : 2) : 0);
      float vals[4];
      #pragma unroll
      for (int fj = 0; fj < 4; fj++) {
        const int m = fj * 16 + lr;
        const int i2 = m >> 3, j2 = m & 7;
        const int labm = (eh ? (i2 < 4 ? 3 : 6) : 0) + (ew ? (j2 < 4 ? 1 : 2) : 0);
        vals[fj] = s[fi][fj][r] + rps[(i1 - i2 + 7) * 15 + (j1 - j2 + 7)]
                 + (labn != labm ? -100.0f : 0.0f);
      }
      float mx = fmaxf(fmaxf(vals[0], vals[1]), fmaxf(vals[2], vals[3]));
      #pragma unroll
      for (int msk = 1; msk < 16; msk <<= 1) mx = fmaxf(mx, __shfl_xor(mx, msk));
      float pe[4]; float sum = 0.f;
      #pragma unroll
      for (int fj = 0; fj < 4; fj++) { pe[fj] = __expf(vals[fj] - mx); sum += pe[fj]; }
      #pragma unroll
      for (int msk = 1; msk < 16; msk <<= 1) sum += __shfl_xor(sum, msk);
      const float rinv = 1.0f / sum;
      #pragma unroll
      for (int fj = 0; fj < 4; fj++)
        P[n * 72 + fj * 16 + lr] = __float2bfloat16(pe[fj] * rinv);
    }
  }
  __syncthreads();

  // O = P V : 4x2 fragments, k = 64 = 2 MFMA steps
  f32x4 o[4][2];
  #pragma unroll
  for (int fi = 0; fi < 4; fi++)
    #pragma unroll
    for (int fd = 0; fd < 2; fd++) o[fi][fd] = z4;
  const bf16* vt = (const bf16*)(smem + 10240);
  #pragma unroll
  for (int ks = 0; ks < 2; ks++) {
    bf16x8 pa[4], vb[2];
    #pragma unroll
    for (int fi = 0; fi < 4; fi++)
      pa[fi] = *(const bf16x8*)(P + (fi * 16 + lr) * 72 + ks * 32 + lg * 8);
    #pragma unroll
    for (int fd = 0; fd < 2; fd++)
      vb[fd] = *(const bf16x8*)(vt + (fd * 16 + lr) * 72 + ks * 32 + lg * 8);
    #pragma unroll
    for (int fi = 0; fi < 4; fi++)
      #pragma unroll
      for (int fd = 0; fd < 2; fd++)
        o[fi][fd] = __builtin_amdgcn_mfma_f32_16x16x32_bf16(pa[fi], vb[fd], o[fi][fd], 0, 0, 0);
  }
  #pragma unroll
  for (int fi = 0; fi < 4; fi++)
    #pragma unroll
    for (int fd = 0; fd < 2; fd++)
      #pragma unroll
      for (int r = 0; r < 4; r++) {
        const int n = fi * 16 + lg * 4 + r;
        outp[((long)b_ * 64 + n) * 192 + head * 32 + fd * 16 + lr] = __float2bfloat16(o[fi][fd][r]);
      }
}

extern "C" void kernel_launch(void* const* d_in, const int* in_sizes, int n_in,
                              void* d_out, int out_size, void* d_ws, size_t ws_size,
                              hipStream_t stream) {
  const float* x      = (const float*)d_in[0];
  const float* qkv_w  = (const float*)d_in[1];
  const float* qkv_b  = (const float*)d_in[2];
  const float* proj_w = (const float*)d_in[3];
  const float* proj_b = (const float*)d_in[4];
  const float* rpb    = (const float*)d_in[5];
  const float* n1_w   = (const float*)d_in[6];
  const float* n1_b   = (const float*)d_in[7];
  const float* n2_w   = (const float*)d_in[8];
  const float* n2_b   = (const float*)d_in[9];
  const float* fc1_w  = (const float*)d_in[10];
  const float* fc1_b  = (const float*)d_in[11];
  const float* fc2_w  = (const float*)d_in[12];
  const float* fc2_b  = (const float*)d_in[13];

  char* ws = (char*)d_ws;
  // workspace layout (total ~673 MB):
  // [0, 884736)            weights bf16
  // [1 MiB, +100663296)    R1: zw -> attn_out -> h_ln  (bf16, M x 192)
  // [101711872, +402653184) R2: qkv (M x 576) -> g (M x 768)  (bf16)
  // [504365056, +201326592) R3: h_buf (M x 192 f32, original token order)
  bf16* qkvw_h  = (bf16*)(ws);
  bf16* projw_h = (bf16*)(ws + 221184);
  bf16* fc1w_h  = (bf16*)(ws + 294912);
  bf16* fc2w_h  = (bf16*)(ws + 589824);
  bf16* r1      = (bf16*)(ws + (1L << 20));
  bf16* r2      = (bf16*)(ws + 101711872L);
  float* hbuf   = (float*)(ws + 504365056L);

  cvt_kernel<<<432, 256, 0, stream>>>(qkv_w, qkvw_h, 110592);
  cvt_kernel<<<144, 256, 0, stream>>>(proj_w, projw_h, 36864);
  cvt_kernel<<<576, 256, 0, stream>>>(fc1_w, fc1w_h, 147456);
  cvt_kernel<<<576, 256, 0, stream>>>(fc2_w, fc2w_h, 147456);

  // LN1 + roll + window partition -> zw (r1)
  ln_kernel<true><<<65536, 256, 0, stream>>>(x, n1_w, n1_b, r1);
  // QKV: zw @ qkv_w^T -> per-(window,head) Q|K|V blocks (r2)
  gemm_bt<0><<<dim3(9, 2048), 256, 0, stream>>>(r1, qkvw_h, qkv_b, 192, r2, nullptr, nullptr);
  // windowed attention -> attn_out (r1)
  attn_kernel<<<24576, 64, 0, stream>>>(r2, rpb, r1);
  // proj + window-reverse + roll + residual -> h_buf (r3, original order)
  gemm_bt<1><<<dim3(3, 2048), 256, 0, stream>>>(r1, projw_h, proj_b, 192, hbuf, x, nullptr);
  // LN2 -> h_ln (r1)
  ln_kernel<false><<<65536, 256, 0, stream>>>(hbuf, n2_w, n2_b, r1);
  // fc1 + gelu -> g (r2)
  gemm_bt<2><<<dim3(12, 2048), 256, 0, stream>>>(r1, fc1w_h, fc1_b, 192, r2, nullptr, nullptr);
  // fc2 + residual -> out (f32)
  gemm_bt<3><<<dim3(3, 2048), 256, 0, stream>>>(r2, fc2w_h, fc2_b, 768, d_out, nullptr, hbuf);
}

// Round 5
// 994.574 us; speedup vs baseline: 1.0557x; 1.0557x over previous
//
#include <hip/hip_runtime.h>
#include <hip/hip_bf16.h>

typedef __attribute__((ext_vector_type(8))) __bf16 bf16x8;
typedef __attribute__((ext_vector_type(4))) float f32x4;
typedef __hip_bfloat16 bf16;

#define SCALE_Q 0.17677669529663687f

// exact-grade GELU: Abramowitz-Stegun 7.1.26 erf (|err| < 1.5e-7)
__device__ inline float gelu_f(float x) {
  const float ax = fabsf(x) * 0.70710678118654752f;
  const float t = __builtin_amdgcn_rcpf(__builtin_fmaf(0.3275911f, ax, 1.0f));
  const float poly = t * __builtin_fmaf(t, __builtin_fmaf(t, __builtin_fmaf(t,
                     __builtin_fmaf(t, 1.061405429f, -1.453152027f),
                     1.421413741f), -0.284496736f), 0.254829592f);
  const float er = __builtin_fmaf(-poly, __expf(-ax * ax), 1.0f);
  return 0.5f * x * (1.0f + copysignf(er, x));
}

// ---------------- weight fp32 -> bf16 ----------------
__global__ void cvt_kernel(const float* __restrict__ in, bf16* __restrict__ out, int n) {
  int i = blockIdx.x * 256 + threadIdx.x;
  if (i < n) out[i] = __float2bfloat16(in[i]);
}

// ---- LayerNorm (optionally fused shifted-window gather), fp32 in -> bf16 out ----
// One wave per token (192 channels = 3 floats/lane), 4 waves/block.
template<bool GATHER>
__global__ __launch_bounds__(256) void ln_kernel(const float* __restrict__ in,
                                                 const float* __restrict__ gw,
                                                 const float* __restrict__ gb,
                                                 bf16* __restrict__ out) {
  const int t = blockIdx.x * 4 + (threadIdx.x >> 6);
  const int lane = threadIdx.x & 63;
  long g;
  if (GATHER) {
    const int b_ = t >> 6, n = t & 63;
    const int b = b_ >> 10, wk = b_ & 1023, wi = wk >> 5, wj = wk & 31;
    const int i_ = n >> 3, j_ = n & 7;
    const int hf = (wi * 8 + i_ + 4) & 255, wf = (wj * 8 + j_ + 4) & 255;
    g = (((long)b * 256 + hf) * 256 + wf) * 192;
  } else {
    g = (long)t * 192;
  }
  const float x0 = in[g + lane], x1 = in[g + 64 + lane], x2 = in[g + 128 + lane];
  float s = x0 + x1 + x2;
  float s2 = x0 * x0 + x1 * x1 + x2 * x2;
  #pragma unroll
  for (int m = 1; m < 64; m <<= 1) { s += __shfl_xor(s, m); s2 += __shfl_xor(s2, m); }
  const float mu = s * (1.0f / 192.0f);
  const float rstd = rsqrtf(s2 * (1.0f / 192.0f) - mu * mu + 1e-5f);
  const long o = (long)t * 192;
  out[o + lane]       = __float2bfloat16((x0 - mu) * rstd * gw[lane]       + gb[lane]);
  out[o + 64 + lane]  = __float2bfloat16((x1 - mu) * rstd * gw[lane + 64]  + gb[lane + 64]);
  out[o + 128 + lane] = __float2bfloat16((x2 - mu) * rstd * gw[lane + 128] + gb[lane + 128]);
}

// ---------------- GEMM: C[m][n] = sum_k A[m][k] * W[n][k] (+bias), bf16 MFMA ----------------
// BM=128 BN=64 BK=64, 256 threads (4 waves, 2x2), XOR-swizzled LDS (16B chunks).
// EPI 0: qkv scatter (+q scale)   EPI 1: proj + window-reverse+roll + residual -> h_buf f32
// EPI 2: fc1 + poly gelu -> bf16  EPI 3: fc2 + h_buf residual -> f32 out
template<int EPI>
__global__ __launch_bounds__(256) void gemm_bt(const bf16* __restrict__ A,
                                               const bf16* __restrict__ Bw,
                                               const float* __restrict__ bias,
                                               int K, void* __restrict__ outp,
                                               const float* __restrict__ aux1,
                                               const float* __restrict__ aux2) {
  __shared__ __align__(16) bf16 Ald[128 * 64];
  __shared__ __align__(16) bf16 Bld[64 * 64];
  const int tid = threadIdx.x;
  const int n0 = blockIdx.x * 64;
  const long m0 = (long)blockIdx.y * 128;
  const int lane = tid & 63, wid = tid >> 6;
  const int wr = (wid >> 1) * 64, wc = (wid & 1) * 32;
  const int lg = lane >> 4, lr = lane & 15;

  f32x4 acc[4][2];
  #pragma unroll
  for (int i = 0; i < 4; i++)
    #pragma unroll
    for (int j = 0; j < 2; j++) acc[i][j] = (f32x4){0.f, 0.f, 0.f, 0.f};

  for (int k0 = 0; k0 < K; k0 += 64) {
    #pragma unroll
    for (int q = 0; q < 4; q++) {
      const int flat = q * 256 + tid, row = flat >> 3, c = flat & 7;
      const uint4 v = *(const uint4*)(A + (m0 + row) * K + k0 + c * 8);
      *(uint4*)((char*)Ald + row * 128 + ((c ^ (row & 7)) * 16)) = v;
    }
    #pragma unroll
    for (int q = 0; q < 2; q++) {
      const int flat = q * 256 + tid, row = flat >> 3, c = flat & 7;
      const uint4 v = *(const uint4*)(Bw + (n0 + row) * K + k0 + c * 8);
      *(uint4*)((char*)Bld + row * 128 + ((c ^ (row & 7)) * 16)) = v;
    }
    __syncthreads();
    #pragma unroll
    for (int ks = 0; ks < 2; ks++) {
      bf16x8 af[4], bfr[2];
      #pragma unroll
      for (int i = 0; i < 4; i++) {
        const int row = wr + i * 16 + lr;
        af[i] = *(const bf16x8*)((const char*)Ald + row * 128 + (((ks * 4 + lg) ^ (row & 7)) * 16));
      }
      #pragma unroll
      for (int j = 0; j < 2; j++) {
        const int row = wc + j * 16 + lr;
        bfr[j] = *(const bf16x8*)((const char*)Bld + row * 128 + (((ks * 4 + lg) ^ (row & 7)) * 16));
      }
      #pragma unroll
      for (int i = 0; i < 4; i++)
        #pragma unroll
        for (int j = 0; j < 2; j++)
          acc[i][j] = __builtin_amdgcn_mfma_f32_16x16x32_bf16(af[i], bfr[j], acc[i][j], 0, 0, 0);
    }
    __syncthreads();
  }

  #pragma unroll
  for (int i = 0; i < 4; i++) {
    #pragma unroll
    for (int j = 0; j < 2; j++) {
      #pragma unroll
      for (int r = 0; r < 4; r++) {
        const long m = m0 + wr + i * 16 + lg * 4 + r;   // token row
        const int cn = n0 + wc + j * 16 + lr;           // output col
        float v = acc[i][j][r] + bias[cn];
        if (EPI == 0) {
          const long b_ = m >> 6; const int n = (int)(m & 63);
          const int which = cn / 192, rem = cn - which * 192, head = rem >> 5, d = rem & 31;
          if (which == 0) v *= SCALE_Q;
          ((bf16*)outp)[((b_ * 6 + head) * 3 + which) * 2048 + n * 32 + d] = __float2bfloat16(v);
        } else if (EPI == 1) {
          const long b_ = m >> 6; const int n = (int)(m & 63);
          const int b = (int)(b_ >> 10), wk = (int)(b_ & 1023), wi = wk >> 5, wj = wk & 31;
          const int i_ = n >> 3, j_ = n & 7;
          const int hf = (wi * 8 + i_ + 4) & 255, wf = (wj * 8 + j_ + 4) & 255;
          const long g = (((long)b * 256 + hf) * 256 + wf) * 192 + cn;
          ((float*)outp)[g] = aux1[g] + v;   // h = shortcut + proj(attn)
        } else if (EPI == 2) {
          ((bf16*)outp)[m * 768 + cn] = __float2bfloat16(gelu_f(v));
        } else {
          ((float*)outp)[m * 192 + cn] = aux2[m * 192 + cn] + v;
        }
      }
    }
  }
}

// ---------------- windowed attention: one wave per (window, head) ----------------
__global__ __launch_bounds__(64) void attn_kernel(const bf16* __restrict__ qkv,
                                                  const float* __restrict__ rpb,
                                                  bf16* __restrict__ outp) {
  // smem: Q[64][40] @0 (5120B), K[64][40] @5120, Vt[32][72] @10240 (4608B)
  // P[64][72] (9216B) overlays Q+K after QK^T
  __shared__ __align__(16) char smem[14848];
  __shared__ float rps[225];
  const int bid = blockIdx.x;
  const int b_ = bid / 6, head = bid - b_ * 6;
  const int lane = threadIdx.x;
  const long base = ((long)b_ * 6 + head) * 3 * 2048;

  for (int t = lane; t < 225; t += 64) rps[t] = rpb[t * 6 + head];

  #pragma unroll
  for (int q = 0; q < 4; q++) {
    const int f = q * 64 + lane, row = f >> 2, c = f & 3;
    *(uint4*)(smem + row * 80 + c * 16) = *(const uint4*)(qkv + base + row * 32 + c * 8);
    *(uint4*)(smem + 5120 + row * 80 + c * 16) = *(const uint4*)(qkv + base + 2048 + row * 32 + c * 8);
  }
  {  // stage V transposed: Vt[d][m]
    const bf16* vsrc = qkv + base + 4096 + lane * 32;
    bf16 vv[32];
    #pragma unroll
    for (int q = 0; q < 4; q++) *(uint4*)&vv[q * 8] = *(const uint4*)(vsrc + q * 8);
    bf16* vt = (bf16*)(smem + 10240);
    #pragma unroll
    for (int d = 0; d < 32; d++) vt[d * 72 + lane] = vv[d];
  }
  __syncthreads();

  const int lg = lane >> 4, lr = lane & 15;
  const f32x4 z4 = {0.f, 0.f, 0.f, 0.f};
  f32x4 s[4][4];
  {  // S = Q K^T : K(dot)=32 = one MFMA step; 4x4 fragments of 16x16
    bf16x8 a[4], b[4];
    #pragma unroll
    for (int fi = 0; fi < 4; fi++)
      a[fi] = *(const bf16x8*)(smem + (fi * 16 + lr) * 80 + lg * 16);
    #pragma unroll
    for (int fj = 0; fj < 4; fj++)
      b[fj] = *(const bf16x8*)(smem + 5120 + (fj * 16 + lr) * 80 + lg * 16);
    #pragma unroll
    for (int fi = 0; fi < 4; fi++)
      #pragma unroll
      for (int fj = 0; fj < 4; fj++)
        s[fi][fj] = __builtin_amdgcn_mfma_f32_16x16x32_bf16(a[fi], b[fj], z4, 0, 0, 0);
  }

  // bias + shift-mask + row softmax; write P (bf16) to LDS
  const int wk = b_ & 1023; const int wi = wk >> 5, wj = wk & 31;
  const bool eh = (wi == 31), ew = (wj == 31);
  bf16* P = (bf16*)smem;
  #pragma unroll
  for (int fi = 0; fi < 4; fi++) {
    #pragma unroll
    for (int r = 0; r < 4; r++) {
      const int n = fi * 16 + lg * 4 + r;
      const int i1 = n >> 3, j1 = n & 7;
      const int labn = (eh ? (i1 < 4 ? 3 : 6) : 0) + (ew ? (j1 < 4 ? 1 : 2) : 0);
      float vals[4];
      #pragma unroll
      for (int fj = 0; fj < 4; fj++) {
        const int m = fj * 16 + lr;
        const int i2 = m >> 3, j2 = m & 7;
        const int labm = (eh ? (i2 < 4 ? 3 : 6) : 0) + (ew ? (j2 < 4 ? 1 : 2) : 0);
        vals[fj] = s[fi][fj][r] + rps[(i1 - i2 + 7) * 15 + (j1 - j2 + 7)]
                 + (labn != labm ? -100.0f : 0.0f);
      }
      float mx = fmaxf(fmaxf(vals[0], vals[1]), fmaxf(vals[2], vals[3]));
      #pragma unroll
      for (int msk = 1; msk < 16; msk <<= 1) mx = fmaxf(mx, __shfl_xor(mx, msk));
      float pe[4]; float sum = 0.f;
      #pragma unroll
      for (int fj = 0; fj < 4; fj++) { pe[fj] = __expf(vals[fj] - mx); sum += pe[fj]; }
      #pragma unroll
      for (int msk = 1; msk < 16; msk <<= 1) sum += __shfl_xor(sum, msk);
      const float rinv = 1.0f / sum;
      #pragma unroll
      for (int fj = 0; fj < 4; fj++)
        P[n * 72 + fj * 16 + lr] = __float2bfloat16(pe[fj] * rinv);
    }
  }
  __syncthreads();

  // O = P V : 4x2 fragments, k = 64 = 2 MFMA steps
  f32x4 o[4][2];
  #pragma unroll
  for (int fi = 0; fi < 4; fi++)
    #pragma unroll
    for (int fd = 0; fd < 2; fd++) o[fi][fd] = z4;
  const bf16* vt = (const bf16*)(smem + 10240);
  #pragma unroll
  for (int ks = 0; ks < 2; ks++) {
    bf16x8 pa[4], vb[2];
    #pragma unroll
    for (int fi = 0; fi < 4; fi++)
      pa[fi] = *(const bf16x8*)(P + (fi * 16 + lr) * 72 + ks * 32 + lg * 8);
    #pragma unroll
    for (int fd = 0; fd < 2; fd++)
      vb[fd] = *(const bf16x8*)(vt + (fd * 16 + lr) * 72 + ks * 32 + lg * 8);
    #pragma unroll
    for (int fi = 0; fi < 4; fi++)
      #pragma unroll
      for (int fd = 0; fd < 2; fd++)
        o[fi][fd] = __builtin_amdgcn_mfma_f32_16x16x32_bf16(pa[fi], vb[fd], o[fi][fd], 0, 0, 0);
  }
  #pragma unroll
  for (int fi = 0; fi < 4; fi++)
    #pragma unroll
    for (int fd = 0; fd < 2; fd++)
      #pragma unroll
      for (int r = 0; r < 4; r++) {
        const int n = fi * 16 + lg * 4 + r;
        outp[((long)b_ * 64 + n) * 192 + head * 32 + fd * 16 + lr] = __float2bfloat16(o[fi][fd][r]);
      }
}

extern "C" void kernel_launch(void* const* d_in, const int* in_sizes, int n_in,
                              void* d_out, int out_size, void* d_ws, size_t ws_size,
                              hipStream_t stream) {
  const float* x      = (const float*)d_in[0];
  const float* qkv_w  = (const float*)d_in[1];
  const float* qkv_b  = (const float*)d_in[2];
  const float* proj_w = (const float*)d_in[3];
  const float* proj_b = (const float*)d_in[4];
  const float* rpb    = (const float*)d_in[5];
  const float* n1_w   = (const float*)d_in[6];
  const float* n1_b   = (const float*)d_in[7];
  const float* n2_w   = (const float*)d_in[8];
  const float* n2_b   = (const float*)d_in[9];
  const float* fc1_w  = (const float*)d_in[10];
  const float* fc1_b  = (const float*)d_in[11];
  const float* fc2_w  = (const float*)d_in[12];
  const float* fc2_b  = (const float*)d_in[13];

  char* ws = (char*)d_ws;
  // workspace layout (total ~673 MB) — exact round-1 proven layout:
  // [0, 884736)            weights bf16
  // [1 MiB, +100663296)    R1: zw -> attn_out -> h_ln  (bf16, M x 192)
  // [101711872, +402653184) R2: qkv (M x 576) -> g (M x 768)  (bf16)
  // [504365056, +201326592) R3: h_buf (M x 192 f32, original token order)
  bf16* qkvw_h  = (bf16*)(ws);
  bf16* projw_h = (bf16*)(ws + 221184);
  bf16* fc1w_h  = (bf16*)(ws + 294912);
  bf16* fc2w_h  = (bf16*)(ws + 589824);
  bf16* r1      = (bf16*)(ws + (1L << 20));
  bf16* r2      = (bf16*)(ws + 101711872L);
  float* hbuf   = (float*)(ws + 504365056L);

  cvt_kernel<<<432, 256, 0, stream>>>(qkv_w, qkvw_h, 110592);
  cvt_kernel<<<144, 256, 0, stream>>>(proj_w, projw_h, 36864);
  cvt_kernel<<<576, 256, 0, stream>>>(fc1_w, fc1w_h, 147456);
  cvt_kernel<<<576, 256, 0, stream>>>(fc2_w, fc2w_h, 147456);

  // LN1 + roll + window partition -> zw (r1)
  ln_kernel<true><<<65536, 256, 0, stream>>>(x, n1_w, n1_b, r1);
  // QKV: zw @ qkv_w^T -> per-(window,head) Q|K|V blocks (r2)
  gemm_bt<0><<<dim3(9, 2048), 256, 0, stream>>>(r1, qkvw_h, qkv_b, 192, r2, nullptr, nullptr);
  // windowed attention -> attn_out (r1)
  attn_kernel<<<24576, 64, 0, stream>>>(r2, rpb, r1);
  // proj + window-reverse + roll + residual -> h_buf (r3, original order)
  gemm_bt<1><<<dim3(3, 2048), 256, 0, stream>>>(r1, projw_h, proj_b, 192, hbuf, x, nullptr);
  // LN2 -> h_ln (r1)
  ln_kernel<false><<<65536, 256, 0, stream>>>(hbuf, n2_w, n2_b, r1);
  // fc1 + gelu -> g (r2)
  gemm_bt<2><<<dim3(12, 2048), 256, 0, stream>>>(r1, fc1w_h, fc1_b, 192, r2, nullptr, nullptr);
  // fc2 + residual -> out (f32)
  gemm_bt<3><<<dim3(3, 2048), 256, 0, stream>>>(r2, fc2w_h, fc2_b, 768, d_out, nullptr, hbuf);
}

// Round 6
// 979.385 us; speedup vs baseline: 1.0720x; 1.0155x over previous
//
#include <hip/hip_runtime.h>
#include <hip/hip_bf16.h>

typedef __attribute__((ext_vector_type(8))) __bf16 bf16x8;
typedef __attribute__((ext_vector_type(4))) float f32x4;
typedef __hip_bfloat16 bf16;

#define SCALE_Q 0.17677669529663687f

// exact-grade GELU: Abramowitz-Stegun 7.1.26 erf (|err| < 1.5e-7)
__device__ inline float gelu_f(float x) {
  const float ax = fabsf(x) * 0.70710678118654752f;
  const float t = __builtin_amdgcn_rcpf(__builtin_fmaf(0.3275911f, ax, 1.0f));
  const float poly = t * __builtin_fmaf(t, __builtin_fmaf(t, __builtin_fmaf(t,
                     __builtin_fmaf(t, 1.061405429f, -1.453152027f),
                     1.421413741f), -0.284496736f), 0.254829592f);
  const float er = __builtin_fmaf(-poly, __expf(-ax * ax), 1.0f);
  return 0.5f * x * (1.0f + copysignf(er, x));
}

// ---------------- weight fp32 -> bf16 ----------------
__global__ void cvt_kernel(const float* __restrict__ in, bf16* __restrict__ out, int n) {
  int i = blockIdx.x * 256 + threadIdx.x;
  if (i < n) out[i] = __float2bfloat16(in[i]);
}

// ---- LayerNorm (optionally fused shifted-window gather), fp32 in -> bf16 out ----
template<bool GATHER>
__global__ __launch_bounds__(256) void ln_kernel(const float* __restrict__ in,
                                                 const float* __restrict__ gw,
                                                 const float* __restrict__ gb,
                                                 bf16* __restrict__ out) {
  const int t = blockIdx.x * 4 + (threadIdx.x >> 6);
  const int lane = threadIdx.x & 63;
  long g;
  if (GATHER) {
    const int b_ = t >> 6, n = t & 63;
    const int b = b_ >> 10, wk = b_ & 1023, wi = wk >> 5, wj = wk & 31;
    const int i_ = n >> 3, j_ = n & 7;
    const int hf = (wi * 8 + i_ + 4) & 255, wf = (wj * 8 + j_ + 4) & 255;
    g = (((long)b * 256 + hf) * 256 + wf) * 192;
  } else {
    g = (long)t * 192;
  }
  const float x0 = in[g + lane], x1 = in[g + 64 + lane], x2 = in[g + 128 + lane];
  float s = x0 + x1 + x2;
  float s2 = x0 * x0 + x1 * x1 + x2 * x2;
  #pragma unroll
  for (int m = 1; m < 64; m <<= 1) { s += __shfl_xor(s, m); s2 += __shfl_xor(s2, m); }
  const float mu = s * (1.0f / 192.0f);
  const float rstd = rsqrtf(s2 * (1.0f / 192.0f) - mu * mu + 1e-5f);
  const long o = (long)t * 192;
  out[o + lane]       = __float2bfloat16((x0 - mu) * rstd * gw[lane]       + gb[lane]);
  out[o + 64 + lane]  = __float2bfloat16((x1 - mu) * rstd * gw[lane + 64]  + gb[lane + 64]);
  out[o + 128 + lane] = __float2bfloat16((x2 - mu) * rstd * gw[lane + 128] + gb[lane + 128]);
}

// ---------------- GEMM: C[m][n] = sum_k A[m][k] * W[n][k] (+bias), bf16 MFMA ----------------
// BM=128 BN=192 BK=64, 256 threads (4 waves 2x2, wave tile 64x96). XOR-swizzled LDS.
// All addressing idioms verbatim from the round-1/5-proven gemm_bt.
// EPI 0: qkv scatter (+q scale)   EPI 1: proj + window-reverse+roll + residual -> h_buf f32
// EPI 2: fc1 + poly gelu -> bf16  EPI 3: fc2 + h_buf residual -> f32 out
template<int EPI>
__global__ __launch_bounds__(256) void gemm_bt(const bf16* __restrict__ A,
                                               const bf16* __restrict__ Bw,
                                               const float* __restrict__ bias,
                                               int K, void* __restrict__ outp,
                                               const float* __restrict__ aux1,
                                               const float* __restrict__ aux2) {
  __shared__ __align__(16) bf16 Ald[128 * 64];
  __shared__ __align__(16) bf16 Bld[192 * 64];
  const int tid = threadIdx.x;
  const int n0 = blockIdx.x * 192;
  const long m0 = (long)blockIdx.y * 128;
  const int lane = tid & 63, wid = tid >> 6;
  const int wr = (wid >> 1) * 64, wc = (wid & 1) * 96;
  const int lg = lane >> 4, lr = lane & 15;

  f32x4 acc[4][6];
  #pragma unroll
  for (int i = 0; i < 4; i++)
    #pragma unroll
    for (int j = 0; j < 6; j++) acc[i][j] = (f32x4){0.f, 0.f, 0.f, 0.f};

  for (int k0 = 0; k0 < K; k0 += 64) {
    #pragma unroll
    for (int q = 0; q < 4; q++) {
      const int flat = q * 256 + tid, row = flat >> 3, c = flat & 7;
      const uint4 v = *(const uint4*)(A + (m0 + row) * K + k0 + c * 8);
      *(uint4*)((char*)Ald + row * 128 + ((c ^ (row & 7)) * 16)) = v;
    }
    #pragma unroll
    for (int q = 0; q < 6; q++) {
      const int flat = q * 256 + tid, row = flat >> 3, c = flat & 7;
      const uint4 v = *(const uint4*)(Bw + (n0 + row) * K + k0 + c * 8);
      *(uint4*)((char*)Bld + row * 128 + ((c ^ (row & 7)) * 16)) = v;
    }
    __syncthreads();
    #pragma unroll
    for (int ks = 0; ks < 2; ks++) {
      bf16x8 af[4], bfr[6];
      #pragma unroll
      for (int i = 0; i < 4; i++) {
        const int row = wr + i * 16 + lr;
        af[i] = *(const bf16x8*)((const char*)Ald + row * 128 + (((ks * 4 + lg) ^ (row & 7)) * 16));
      }
      #pragma unroll
      for (int j = 0; j < 6; j++) {
        const int row = wc + j * 16 + lr;
        bfr[j] = *(const bf16x8*)((const char*)Bld + row * 128 + (((ks * 4 + lg) ^ (row & 7)) * 16));
      }
      #pragma unroll
      for (int i = 0; i < 4; i++)
        #pragma unroll
        for (int j = 0; j < 6; j++)
          acc[i][j] = __builtin_amdgcn_mfma_f32_16x16x32_bf16(af[i], bfr[j], acc[i][j], 0, 0, 0);
    }
    __syncthreads();
  }

  #pragma unroll
  for (int i = 0; i < 4; i++) {
    #pragma unroll
    for (int j = 0; j < 6; j++) {
      #pragma unroll
      for (int r = 0; r < 4; r++) {
        const long m = m0 + wr + i * 16 + lg * 4 + r;   // token row
        const int cn = n0 + wc + j * 16 + lr;           // output col
        float v = acc[i][j][r] + bias[cn];
        if (EPI == 0) {
          const long b_ = m >> 6; const int n = (int)(m & 63);
          const int which = cn / 192, rem = cn - which * 192, head = rem >> 5, d = rem & 31;
          if (which == 0) v *= SCALE_Q;
          ((bf16*)outp)[((b_ * 6 + head) * 3 + which) * 2048 + n * 32 + d] = __float2bfloat16(v);
        } else if (EPI == 1) {
          const long b_ = m >> 6; const int n = (int)(m & 63);
          const int b = (int)(b_ >> 10), wk = (int)(b_ & 1023), wi = wk >> 5, wj = wk & 31;
          const int i_ = n >> 3, j_ = n & 7;
          const int hf = (wi * 8 + i_ + 4) & 255, wf = (wj * 8 + j_ + 4) & 255;
          const long g = (((long)b * 256 + hf) * 256 + wf) * 192 + cn;
          ((float*)outp)[g] = aux1[g] + v;   // h = shortcut + proj(attn)
        } else if (EPI == 2) {
          ((bf16*)outp)[m * 768 + cn] = __float2bfloat16(gelu_f(v));
        } else {
          ((float*)outp)[m * 192 + cn] = aux2[m * 192 + cn] + v;
        }
      }
    }
  }
}

// ---------------- windowed attention: one wave per (window, head) — exact round-1 ----------------
__global__ __launch_bounds__(64) void attn_kernel(const bf16* __restrict__ qkv,
                                                  const float* __restrict__ rpb,
                                                  bf16* __restrict__ outp) {
  __shared__ __align__(16) char smem[14848];
  __shared__ float rps[225];
  const int bid = blockIdx.x;
  const int b_ = bid / 6, head = bid - b_ * 6;
  const int lane = threadIdx.x;
  const long base = ((long)b_ * 6 + head) * 3 * 2048;

  for (int t = lane; t < 225; t += 64) rps[t] = rpb[t * 6 + head];

  #pragma unroll
  for (int q = 0; q < 4; q++) {
    const int f = q * 64 + lane, row = f >> 2, c = f & 3;
    *(uint4*)(smem + row * 80 + c * 16) = *(const uint4*)(qkv + base + row * 32 + c * 8);
    *(uint4*)(smem + 5120 + row * 80 + c * 16) = *(const uint4*)(qkv + base + 2048 + row * 32 + c * 8);
  }
  {  // stage V transposed: Vt[d][m]
    const bf16* vsrc = qkv + base + 4096 + lane * 32;
    bf16 vv[32];
    #pragma unroll
    for (int q = 0; q < 4; q++) *(uint4*)&vv[q * 8] = *(const uint4*)(vsrc + q * 8);
    bf16* vt = (bf16*)(smem + 10240);
    #pragma unroll
    for (int d = 0; d < 32; d++) vt[d * 72 + lane] = vv[d];
  }
  __syncthreads();

  const int lg = lane >> 4, lr = lane & 15;
  const f32x4 z4 = {0.f, 0.f, 0.f, 0.f};
  f32x4 s[4][4];
  {
    bf16x8 a[4], b[4];
    #pragma unroll
    for (int fi = 0; fi < 4; fi++)
      a[fi] = *(const bf16x8*)(smem + (fi * 16 + lr) * 80 + lg * 16);
    #pragma unroll
    for (int fj = 0; fj < 4; fj++)
      b[fj] = *(const bf16x8*)(smem + 5120 + (fj * 16 + lr) * 80 + lg * 16);
    #pragma unroll
    for (int fi = 0; fi < 4; fi++)
      #pragma unroll
      for (int fj = 0; fj < 4; fj++)
        s[fi][fj] = __builtin_amdgcn_mfma_f32_16x16x32_bf16(a[fi], b[fj], z4, 0, 0, 0);
  }

  const int wk = b_ & 1023; const int wi = wk >> 5, wj = wk & 31;
  const bool eh = (wi == 31), ew = (wj == 31);
  bf16* P = (bf16*)smem;
  #pragma unroll
  for (int fi = 0; fi < 4; fi++) {
    #pragma unroll
    for (int r = 0; r < 4; r++) {
      const int n = fi * 16 + lg * 4 + r;
      const int i1 = n >> 3, j1 = n & 7;
      const int labn = (eh ? (i1 < 4 ? 3 : 6) : 0) + (ew ? (j1 < 4 ? 1 : 2) : 0);
      float vals[4];
      #pragma unroll
      for (int fj = 0; fj < 4; fj++) {
        const int m = fj * 16 + lr;
        const int i2 = m >> 3, j2 = m & 7;
        const int labm = (eh ? (i2 < 4 ? 3 : 6) : 0) + (ew ? (j2 < 4 ? 1 : 2) : 0);
        vals[fj] = s[fi][fj][r] + rps[(i1 - i2 + 7) * 15 + (j1 - j2 + 7)]
                 + (labn != labm ? -100.0f : 0.0f);
      }
      float mx = fmaxf(fmaxf(vals[0], vals[1]), fmaxf(vals[2], vals[3]));
      #pragma unroll
      for (int msk = 1; msk < 16; msk <<= 1) mx = fmaxf(mx, __shfl_xor(mx, msk));
      float pe[4]; float sum = 0.f;
      #pragma unroll
      for (int fj = 0; fj < 4; fj++) { pe[fj] = __expf(vals[fj] - mx); sum += pe[fj]; }
      #pragma unroll
      for (int msk = 1; msk < 16; msk <<= 1) sum += __shfl_xor(sum, msk);
      const float rinv = 1.0f / sum;
      #pragma unroll
      for (int fj = 0; fj < 4; fj++)
        P[n * 72 + fj * 16 + lr] = __float2bfloat16(pe[fj] * rinv);
    }
  }
  __syncthreads();

  f32x4 o[4][2];
  #pragma unroll
  for (int fi = 0; fi < 4; fi++)
    #pragma unroll
    for (int fd = 0; fd < 2; fd++) o[fi][fd] = z4;
  const bf16* vt = (const bf16*)(smem + 10240);
  #pragma unroll
  for (int ks = 0; ks < 2; ks++) {
    bf16x8 pa[4], vb[2];
    #pragma unroll
    for (int fi = 0; fi < 4; fi++)
      pa[fi] = *(const bf16x8*)(P + (fi * 16 + lr) * 72 + ks * 32 + lg * 8);
    #pragma unroll
    for (int fd = 0; fd < 2; fd++)
      vb[fd] = *(const bf16x8*)(vt + (fd * 16 + lr) * 72 + ks * 32 + lg * 8);
    #pragma unroll
    for (int fi = 0; fi < 4; fi++)
      #pragma unroll
      for (int fd = 0; fd < 2; fd++)
        o[fi][fd] = __builtin_amdgcn_mfma_f32_16x16x32_bf16(pa[fi], vb[fd], o[fi][fd], 0, 0, 0);
  }
  #pragma unroll
  for (int fi = 0; fi < 4; fi++)
    #pragma unroll
    for (int fd = 0; fd < 2; fd++)
      #pragma unroll
      for (int r = 0; r < 4; r++) {
        const int n = fi * 16 + lg * 4 + r;
        outp[((long)b_ * 64 + n) * 192 + head * 32 + fd * 16 + lr] = __float2bfloat16(o[fi][fd][r]);
      }
}

extern "C" void kernel_launch(void* const* d_in, const int* in_sizes, int n_in,
                              void* d_out, int out_size, void* d_ws, size_t ws_size,
                              hipStream_t stream) {
  const float* x      = (const float*)d_in[0];
  const float* qkv_w  = (const float*)d_in[1];
  const float* qkv_b  = (const float*)d_in[2];
  const float* proj_w = (const float*)d_in[3];
  const float* proj_b = (const float*)d_in[4];
  const float* rpb    = (const float*)d_in[5];
  const float* n1_w   = (const float*)d_in[6];
  const float* n1_b   = (const float*)d_in[7];
  const float* n2_w   = (const float*)d_in[8];
  const float* n2_b   = (const float*)d_in[9];
  const float* fc1_w  = (const float*)d_in[10];
  const float* fc1_b  = (const float*)d_in[11];
  const float* fc2_w  = (const float*)d_in[12];
  const float* fc2_b  = (const float*)d_in[13];

  char* ws = (char*)d_ws;
  // workspace layout — exact round-1/5 proven layout:
  // [0, 884736)             weights bf16
  // [1 MiB, +100663296)     R1: zw -> attn_out -> h_ln  (bf16, M x 192)
  // [101711872, +402653184) R2: qkv (M x 576) -> g (M x 768)  (bf16)
  // [504365056, +201326592) R3: h_buf (M x 192 f32, original token order)
  bf16* qkvw_h  = (bf16*)(ws);
  bf16* projw_h = (bf16*)(ws + 221184);
  bf16* fc1w_h  = (bf16*)(ws + 294912);
  bf16* fc2w_h  = (bf16*)(ws + 589824);
  bf16* r1      = (bf16*)(ws + (1L << 20));
  bf16* r2      = (bf16*)(ws + 101711872L);
  float* hbuf   = (float*)(ws + 504365056L);

  cvt_kernel<<<432, 256, 0, stream>>>(qkv_w, qkvw_h, 110592);
  cvt_kernel<<<144, 256, 0, stream>>>(proj_w, projw_h, 36864);
  cvt_kernel<<<576, 256, 0, stream>>>(fc1_w, fc1w_h, 147456);
  cvt_kernel<<<576, 256, 0, stream>>>(fc2_w, fc2w_h, 147456);

  // LN1 + roll + window partition -> zw (r1)
  ln_kernel<true><<<65536, 256, 0, stream>>>(x, n1_w, n1_b, r1);
  // QKV: zw @ qkv_w^T -> per-(window,head) Q|K|V blocks (r2)
  gemm_bt<0><<<dim3(3, 2048), 256, 0, stream>>>(r1, qkvw_h, qkv_b, 192, r2, nullptr, nullptr);
  // windowed attention -> attn_out (r1)
  attn_kernel<<<24576, 64, 0, stream>>>(r2, rpb, r1);
  // proj + window-reverse + roll + residual -> h_buf (r3, original order)
  gemm_bt<1><<<dim3(1, 2048), 256, 0, stream>>>(r1, projw_h, proj_b, 192, hbuf, x, nullptr);
  // LN2 -> h_ln (r1)
  ln_kernel<false><<<65536, 256, 0, stream>>>(hbuf, n2_w, n2_b, r1);
  // fc1 + gelu -> g (r2)
  gemm_bt<2><<<dim3(4, 2048), 256, 0, stream>>>(r1, fc1w_h, fc1_b, 192, r2, nullptr, nullptr);
  // fc2 + residual -> out (f32)
  gemm_bt<3><<<dim3(1, 2048), 256, 0, stream>>>(r2, fc2w_h, fc2_b, 768, d_out, nullptr, hbuf);
}

// Round 7
// 976.943 us; speedup vs baseline: 1.0747x; 1.0025x over previous
//
#include <hip/hip_runtime.h>
#include <hip/hip_bf16.h>

typedef __attribute__((ext_vector_type(8))) __bf16 bf16x8;
typedef __attribute__((ext_vector_type(4))) float f32x4;
typedef __hip_bfloat16 bf16;

#define SCALE_Q 0.17677669529663687f

// global_load_lds: LDS dest linear (wave-uniform base + lane*16), source pre-swizzled per-lane.
#define LDSP(p) ((__attribute__((address_space(3))) unsigned int*)(unsigned long long)(p))
#define GPTR(p) ((const __attribute__((address_space(1))) unsigned int*)(unsigned long long)(p))
#define GLD16(gp, lp) __builtin_amdgcn_global_load_lds(GPTR(gp), LDSP(lp), 16, 0, 0)

// exact-grade GELU: Abramowitz-Stegun 7.1.26 erf (|err| < 1.5e-7)
__device__ inline float gelu_f(float x) {
  const float ax = fabsf(x) * 0.70710678118654752f;
  const float t = __builtin_amdgcn_rcpf(__builtin_fmaf(0.3275911f, ax, 1.0f));
  const float poly = t * __builtin_fmaf(t, __builtin_fmaf(t, __builtin_fmaf(t,
                     __builtin_fmaf(t, 1.061405429f, -1.453152027f),
                     1.421413741f), -0.284496736f), 0.254829592f);
  const float er = __builtin_fmaf(-poly, __expf(-ax * ax), 1.0f);
  return 0.5f * x * (1.0f + copysignf(er, x));
}

// ---------------- weight fp32 -> bf16 ----------------
__global__ void cvt_kernel(const float* __restrict__ in, bf16* __restrict__ out, int n) {
  int i = blockIdx.x * 256 + threadIdx.x;
  if (i < n) out[i] = __float2bfloat16(in[i]);
}

// ---- LayerNorm (optionally fused shifted-window gather), fp32 in -> bf16 out ----
template<bool GATHER>
__global__ __launch_bounds__(256) void ln_kernel(const float* __restrict__ in,
                                                 const float* __restrict__ gw,
                                                 const float* __restrict__ gb,
                                                 bf16* __restrict__ out) {
  const int t = blockIdx.x * 4 + (threadIdx.x >> 6);
  const int lane = threadIdx.x & 63;
  long g;
  if (GATHER) {
    const int b_ = t >> 6, n = t & 63;
    const int b = b_ >> 10, wk = b_ & 1023, wi = wk >> 5, wj = wk & 31;
    const int i_ = n >> 3, j_ = n & 7;
    const int hf = (wi * 8 + i_ + 4) & 255, wf = (wj * 8 + j_ + 4) & 255;
    g = (((long)b * 256 + hf) * 256 + wf) * 192;
  } else {
    g = (long)t * 192;
  }
  const float x0 = in[g + lane], x1 = in[g + 64 + lane], x2 = in[g + 128 + lane];
  float s = x0 + x1 + x2;
  float s2 = x0 * x0 + x1 * x1 + x2 * x2;
  #pragma unroll
  for (int m = 1; m < 64; m <<= 1) { s += __shfl_xor(s, m); s2 += __shfl_xor(s2, m); }
  const float mu = s * (1.0f / 192.0f);
  const float rstd = rsqrtf(s2 * (1.0f / 192.0f) - mu * mu + 1e-5f);
  const long o = (long)t * 192;
  out[o + lane]       = __float2bfloat16((x0 - mu) * rstd * gw[lane]       + gb[lane]);
  out[o + 64 + lane]  = __float2bfloat16((x1 - mu) * rstd * gw[lane + 64]  + gb[lane + 64]);
  out[o + 128 + lane] = __float2bfloat16((x2 - mu) * rstd * gw[lane + 128] + gb[lane + 128]);
}

// ---------------- GEMM: C[m][n] = sum_k A[m][k] * W[n][k] (+bias), bf16 MFMA ----------------
// BM=128 BN=192 BK=64, 256 threads (4 waves 2x2, wave tile 64x96).
// Staging via global_load_lds width-16: linear LDS dest, inverse-swizzled source; LDS
// contents bit-identical to the proven reg-staged layout (slot l7 of row R = chunk l7^(R&7)).
// EPI 0: qkv scatter (+q scale)   EPI 1: proj + window-reverse+roll + residual -> h_buf f32
// EPI 2: fc1 + poly gelu -> bf16  EPI 3: fc2 + h_buf residual -> f32 out
template<int EPI>
__global__ __launch_bounds__(256) void gemm_bt(const bf16* __restrict__ A,
                                               const bf16* __restrict__ Bw,
                                               const float* __restrict__ bias,
                                               int K, void* __restrict__ outp,
                                               const float* __restrict__ aux1,
                                               const float* __restrict__ aux2) {
  __shared__ __align__(16) bf16 Ald[128 * 64];
  __shared__ __align__(16) bf16 Bld[192 * 64];
  const int tid = threadIdx.x;
  const int n0 = blockIdx.x * 192;
  const long m0 = (long)blockIdx.y * 128;
  const int lane = tid & 63, wid = tid >> 6;
  const int wr = (wid >> 1) * 64, wc = (wid & 1) * 96;
  const int lg = lane >> 4, lr = lane & 15;
  const int l3 = lane >> 3, l7 = lane & 7;
  const int chunk = l7 ^ l3;  // involutive source swizzle

  // per-wave staging pointers: A rows wid*32..+32, B rows wid*48..+48 (both ≡0 mod 8)
  const bf16* aptr = A + (m0 + wid * 32 + l3) * (long)K + chunk * 8;
  const bf16* bptr = Bw + (n0 + wid * 48 + l3) * (long)K + chunk * 8;
  char* alds = (char*)Ald + wid * 32 * 128;
  char* blds = (char*)Bld + wid * 48 * 128;
  const long rk8 = 8 * (long)K;

  f32x4 acc[4][6];
  #pragma unroll
  for (int i = 0; i < 4; i++)
    #pragma unroll
    for (int j = 0; j < 6; j++) acc[i][j] = (f32x4){0.f, 0.f, 0.f, 0.f};

  for (int k0 = 0; k0 < K; k0 += 64) {
    GLD16(aptr + k0, alds);
    GLD16(aptr + rk8 + k0, alds + 1024);
    GLD16(aptr + 2 * rk8 + k0, alds + 2048);
    GLD16(aptr + 3 * rk8 + k0, alds + 3072);
    GLD16(bptr + k0, blds);
    GLD16(bptr + rk8 + k0, blds + 1024);
    GLD16(bptr + 2 * rk8 + k0, blds + 2048);
    GLD16(bptr + 3 * rk8 + k0, blds + 3072);
    GLD16(bptr + 4 * rk8 + k0, blds + 4096);
    GLD16(bptr + 5 * rk8 + k0, blds + 5120);
    __syncthreads();
    #pragma unroll
    for (int ks = 0; ks < 2; ks++) {
      bf16x8 af[4], bfr[6];
      #pragma unroll
      for (int i = 0; i < 4; i++) {
        const int row = wr + i * 16 + lr;
        af[i] = *(const bf16x8*)((const char*)Ald + row * 128 + (((ks * 4 + lg) ^ (row & 7)) * 16));
      }
      #pragma unroll
      for (int j = 0; j < 6; j++) {
        const int row = wc + j * 16 + lr;
        bfr[j] = *(const bf16x8*)((const char*)Bld + row * 128 + (((ks * 4 + lg) ^ (row & 7)) * 16));
      }
      #pragma unroll
      for (int i = 0; i < 4; i++)
        #pragma unroll
        for (int j = 0; j < 6; j++)
          acc[i][j] = __builtin_amdgcn_mfma_f32_16x16x32_bf16(af[i], bfr[j], acc[i][j], 0, 0, 0);
    }
    __syncthreads();
  }

  #pragma unroll
  for (int i = 0; i < 4; i++) {
    #pragma unroll
    for (int j = 0; j < 6; j++) {
      #pragma unroll
      for (int r = 0; r < 4; r++) {
        const long m = m0 + wr + i * 16 + lg * 4 + r;   // token row
        const int cn = n0 + wc + j * 16 + lr;           // output col
        float v = acc[i][j][r] + bias[cn];
        if (EPI == 0) {
          const long b_ = m >> 6; const int n = (int)(m & 63);
          const int which = cn / 192, rem = cn - which * 192, head = rem >> 5, d = rem & 31;
          if (which == 0) v *= SCALE_Q;
          ((bf16*)outp)[((b_ * 6 + head) * 3 + which) * 2048 + n * 32 + d] = __float2bfloat16(v);
        } else if (EPI == 1) {
          const long b_ = m >> 6; const int n = (int)(m & 63);
          const int b = (int)(b_ >> 10), wk = (int)(b_ & 1023), wi = wk >> 5, wj = wk & 31;
          const int i_ = n >> 3, j_ = n & 7;
          const int hf = (wi * 8 + i_ + 4) & 255, wf = (wj * 8 + j_ + 4) & 255;
          const long g = (((long)b * 256 + hf) * 256 + wf) * 192 + cn;
          ((float*)outp)[g] = aux1[g] + v;   // h = shortcut + proj(attn)
        } else if (EPI == 2) {
          ((bf16*)outp)[m * 768 + cn] = __float2bfloat16(gelu_f(v));
        } else {
          ((float*)outp)[m * 192 + cn] = aux2[m * 192 + cn] + v;
        }
      }
    }
  }
}

// ---------------- windowed attention: one wave per (window, head) — exact round-1 ----------------
__global__ __launch_bounds__(64) void attn_kernel(const bf16* __restrict__ qkv,
                                                  const float* __restrict__ rpb,
                                                  bf16* __restrict__ outp) {
  __shared__ __align__(16) char smem[14848];
  __shared__ float rps[225];
  const int bid = blockIdx.x;
  const int b_ = bid / 6, head = bid - b_ * 6;
  const int lane = threadIdx.x;
  const long base = ((long)b_ * 6 + head) * 3 * 2048;

  for (int t = lane; t < 225; t += 64) rps[t] = rpb[t * 6 + head];

  #pragma unroll
  for (int q = 0; q < 4; q++) {
    const int f = q * 64 + lane, row = f >> 2, c = f & 3;
    *(uint4*)(smem + row * 80 + c * 16) = *(const uint4*)(qkv + base + row * 32 + c * 8);
    *(uint4*)(smem + 5120 + row * 80 + c * 16) = *(const uint4*)(qkv + base + 2048 + row * 32 + c * 8);
  }
  {  // stage V transposed: Vt[d][m]
    const bf16* vsrc = qkv + base + 4096 + lane * 32;
    bf16 vv[32];
    #pragma unroll
    for (int q = 0; q < 4; q++) *(uint4*)&vv[q * 8] = *(const uint4*)(vsrc + q * 8);
    bf16* vt = (bf16*)(smem + 10240);
    #pragma unroll
    for (int d = 0; d < 32; d++) vt[d * 72 + lane] = vv[d];
  }
  __syncthreads();

  const int lg = lane >> 4, lr = lane & 15;
  const f32x4 z4 = {0.f, 0.f, 0.f, 0.f};
  f32x4 s[4][4];
  {
    bf16x8 a[4], b[4];
    #pragma unroll
    for (int fi = 0; fi < 4; fi++)
      a[fi] = *(const bf16x8*)(smem + (fi * 16 + lr) * 80 + lg * 16);
    #pragma unroll
    for (int fj = 0; fj < 4; fj++)
      b[fj] = *(const bf16x8*)(smem + 5120 + (fj * 16 + lr) * 80 + lg * 16);
    #pragma unroll
    for (int fi = 0; fi < 4; fi++)
      #pragma unroll
      for (int fj = 0; fj < 4; fj++)
        s[fi][fj] = __builtin_amdgcn_mfma_f32_16x16x32_bf16(a[fi], b[fj], z4, 0, 0, 0);
  }

  const int wk = b_ & 1023; const int wi = wk >> 5, wj = wk & 31;
  const bool eh = (wi == 31), ew = (wj == 31);
  bf16* P = (bf16*)smem;
  #pragma unroll
  for (int fi = 0; fi < 4; fi++) {
    #pragma unroll
    for (int r = 0; r < 4; r++) {
      const int n = fi * 16 + lg * 4 + r;
      const int i1 = n >> 3, j1 = n & 7;
      const int labn = (eh ? (i1 < 4 ? 3 : 6) : 0) + (ew ? (j1 < 4 ? 1 : 2) : 0);
      float vals[4];
      #pragma unroll
      for (int fj = 0; fj < 4; fj++) {
        const int m = fj * 16 + lr;
        const int i2 = m >> 3, j2 = m & 7;
        const int labm = (eh ? (i2 < 4 ? 3 : 6) : 0) + (ew ? (j2 < 4 ? 1 : 2) : 0);
        vals[fj] = s[fi][fj][r] + rps[(i1 - i2 + 7) * 15 + (j1 - j2 + 7)]
                 + (labn != labm ? -100.0f : 0.0f);
      }
      float mx = fmaxf(fmaxf(vals[0], vals[1]), fmaxf(vals[2], vals[3]));
      #pragma unroll
      for (int msk = 1; msk < 16; msk <<= 1) mx = fmaxf(mx, __shfl_xor(mx, msk));
      float pe[4]; float sum = 0.f;
      #pragma unroll
      for (int fj = 0; fj < 4; fj++) { pe[fj] = __expf(vals[fj] - mx); sum += pe[fj]; }
      #pragma unroll
      for (int msk = 1; msk < 16; msk <<= 1) sum += __shfl_xor(sum, msk);
      const float rinv = 1.0f / sum;
      #pragma unroll
      for (int fj = 0; fj < 4; fj++)
        P[n * 72 + fj * 16 + lr] = __float2bfloat16(pe[fj] * rinv);
    }
  }
  __syncthreads();

  f32x4 o[4][2];
  #pragma unroll
  for (int fi = 0; fi < 4; fi++)
    #pragma unroll
    for (int fd = 0; fd < 2; fd++) o[fi][fd] = z4;
  const bf16* vt = (const bf16*)(smem + 10240);
  #pragma unroll
  for (int ks = 0; ks < 2; ks++) {
    bf16x8 pa[4], vb[2];
    #pragma unroll
    for (int fi = 0; fi < 4; fi++)
      pa[fi] = *(const bf16x8*)(P + (fi * 16 + lr) * 72 + ks * 32 + lg * 8);
    #pragma unroll
    for (int fd = 0; fd < 2; fd++)
      vb[fd] = *(const bf16x8*)(vt + (fd * 16 + lr) * 72 + ks * 32 + lg * 8);
    #pragma unroll
    for (int fi = 0; fi < 4; fi++)
      #pragma unroll
      for (int fd = 0; fd < 2; fd++)
        o[fi][fd] = __builtin_amdgcn_mfma_f32_16x16x32_bf16(pa[fi], vb[fd], o[fi][fd], 0, 0, 0);
  }
  #pragma unroll
  for (int fi = 0; fi < 4; fi++)
    #pragma unroll
    for (int fd = 0; fd < 2; fd++)
      #pragma unroll
      for (int r = 0; r < 4; r++) {
        const int n = fi * 16 + lg * 4 + r;
        outp[((long)b_ * 64 + n) * 192 + head * 32 + fd * 16 + lr] = __float2bfloat16(o[fi][fd][r]);
      }
}

extern "C" void kernel_launch(void* const* d_in, const int* in_sizes, int n_in,
                              void* d_out, int out_size, void* d_ws, size_t ws_size,
                              hipStream_t stream) {
  const float* x      = (const float*)d_in[0];
  const float* qkv_w  = (const float*)d_in[1];
  const float* qkv_b  = (const float*)d_in[2];
  const float* proj_w = (const float*)d_in[3];
  const float* proj_b = (const float*)d_in[4];
  const float* rpb    = (const float*)d_in[5];
  const float* n1_w   = (const float*)d_in[6];
  const float* n1_b   = (const float*)d_in[7];
  const float* n2_w   = (const float*)d_in[8];
  const float* n2_b   = (const float*)d_in[9];
  const float* fc1_w  = (const float*)d_in[10];
  const float* fc1_b  = (const float*)d_in[11];
  const float* fc2_w  = (const float*)d_in[12];
  const float* fc2_b  = (const float*)d_in[13];

  char* ws = (char*)d_ws;
  // workspace layout — exact round-1/5 proven layout:
  // [0, 884736)             weights bf16
  // [1 MiB, +100663296)     R1: zw -> attn_out -> h_ln  (bf16, M x 192)
  // [101711872, +402653184) R2: qkv (M x 576) -> g (M x 768)  (bf16)
  // [504365056, +201326592) R3: h_buf (M x 192 f32, original token order)
  bf16* qkvw_h  = (bf16*)(ws);
  bf16* projw_h = (bf16*)(ws + 221184);
  bf16* fc1w_h  = (bf16*)(ws + 294912);
  bf16* fc2w_h  = (bf16*)(ws + 589824);
  bf16* r1      = (bf16*)(ws + (1L << 20));
  bf16* r2      = (bf16*)(ws + 101711872L);
  float* hbuf   = (float*)(ws + 504365056L);

  cvt_kernel<<<432, 256, 0, stream>>>(qkv_w, qkvw_h, 110592);
  cvt_kernel<<<144, 256, 0, stream>>>(proj_w, projw_h, 36864);
  cvt_kernel<<<576, 256, 0, stream>>>(fc1_w, fc1w_h, 147456);
  cvt_kernel<<<576, 256, 0, stream>>>(fc2_w, fc2w_h, 147456);

  // LN1 + roll + window partition -> zw (r1)
  ln_kernel<true><<<65536, 256, 0, stream>>>(x, n1_w, n1_b, r1);
  // QKV: zw @ qkv_w^T -> per-(window,head) Q|K|V blocks (r2)
  gemm_bt<0><<<dim3(3, 2048), 256, 0, stream>>>(r1, qkvw_h, qkv_b, 192, r2, nullptr, nullptr);
  // windowed attention -> attn_out (r1)
  attn_kernel<<<24576, 64, 0, stream>>>(r2, rpb, r1);
  // proj + window-reverse + roll + residual -> h_buf (r3, original order)
  gemm_bt<1><<<dim3(1, 2048), 256, 0, stream>>>(r1, projw_h, proj_b, 192, hbuf, x, nullptr);
  // LN2 -> h_ln (r1)
  ln_kernel<false><<<65536, 256, 0, stream>>>(hbuf, n2_w, n2_b, r1);
  // fc1 + gelu -> g (r2)
  gemm_bt<2><<<dim3(4, 2048), 256, 0, stream>>>(r1, fc1w_h, fc1_b, 192, r2, nullptr, nullptr);
  // fc2 + residual -> out (f32)
  gemm_bt<3><<<dim3(1, 2048), 256, 0, stream>>>(r2, fc2w_h, fc2_b, 768, d_out, nullptr, hbuf);
}

// Round 8
// 958.464 us; speedup vs baseline: 1.0954x; 1.0193x over previous
//
#include <hip/hip_runtime.h>
#include <hip/hip_bf16.h>

typedef __attribute__((ext_vector_type(8))) __bf16 bf16x8;
typedef __attribute__((ext_vector_type(4))) float f32x4;
typedef __hip_bfloat16 bf16;

#define SCALE_Q 0.17677669529663687f

// global_load_lds: LDS dest linear (wave-uniform base + lane*16), source pre-swizzled per-lane.
#define LDSP(p) ((__attribute__((address_space(3))) unsigned int*)(unsigned long long)(p))
#define GPTR(p) ((const __attribute__((address_space(1))) unsigned int*)(unsigned long long)(p))
#define GLD16(gp, lp) __builtin_amdgcn_global_load_lds(GPTR(gp), LDSP(lp), 16, 0, 0)

// exact-grade GELU: Abramowitz-Stegun 7.1.26 erf (|err| < 1.5e-7)
__device__ inline float gelu_f(float x) {
  const float ax = fabsf(x) * 0.70710678118654752f;
  const float t = __builtin_amdgcn_rcpf(__builtin_fmaf(0.3275911f, ax, 1.0f));
  const float poly = t * __builtin_fmaf(t, __builtin_fmaf(t, __builtin_fmaf(t,
                     __builtin_fmaf(t, 1.061405429f, -1.453152027f),
                     1.421413741f), -0.284496736f), 0.254829592f);
  const float er = __builtin_fmaf(-poly, __expf(-ax * ax), 1.0f);
  return 0.5f * x * (1.0f + copysignf(er, x));
}

// ---------------- weight fp32 -> bf16 ----------------
__global__ void cvt_kernel(const float* __restrict__ in, bf16* __restrict__ out, int n) {
  int i = blockIdx.x * 256 + threadIdx.x;
  if (i < n) out[i] = __float2bfloat16(in[i]);
}

// ---- LayerNorm (optionally fused shifted-window gather), fp32 in -> bf16 out ----
template<bool GATHER>
__global__ __launch_bounds__(256) void ln_kernel(const float* __restrict__ in,
                                                 const float* __restrict__ gw,
                                                 const float* __restrict__ gb,
                                                 bf16* __restrict__ out) {
  const int t = blockIdx.x * 4 + (threadIdx.x >> 6);
  const int lane = threadIdx.x & 63;
  long g;
  if (GATHER) {
    const int b_ = t >> 6, n = t & 63;
    const int b = b_ >> 10, wk = b_ & 1023, wi = wk >> 5, wj = wk & 31;
    const int i_ = n >> 3, j_ = n & 7;
    const int hf = (wi * 8 + i_ + 4) & 255, wf = (wj * 8 + j_ + 4) & 255;
    g = (((long)b * 256 + hf) * 256 + wf) * 192;
  } else {
    g = (long)t * 192;
  }
  const float x0 = in[g + lane], x1 = in[g + 64 + lane], x2 = in[g + 128 + lane];
  float s = x0 + x1 + x2;
  float s2 = x0 * x0 + x1 * x1 + x2 * x2;
  #pragma unroll
  for (int m = 1; m < 64; m <<= 1) { s += __shfl_xor(s, m); s2 += __shfl_xor(s2, m); }
  const float mu = s * (1.0f / 192.0f);
  const float rstd = rsqrtf(s2 * (1.0f / 192.0f) - mu * mu + 1e-5f);
  const long o = (long)t * 192;
  out[o + lane]       = __float2bfloat16((x0 - mu) * rstd * gw[lane]       + gb[lane]);
  out[o + 64 + lane]  = __float2bfloat16((x1 - mu) * rstd * gw[lane + 64]  + gb[lane + 64]);
  out[o + 128 + lane] = __float2bfloat16((x2 - mu) * rstd * gw[lane + 128] + gb[lane + 128]);
}

// ---------------- GEMM: C[m][n] = sum_k A[m][k] * W[n][k] (+bias), bf16 MFMA ----------------
// BM=128 BN=192 BK=64, 256 threads (4 waves 2x2, wave tile 64x96).
// __launch_bounds__(256, 2): 2 waves/EU floor -> 256-VGPR budget, kills the spill
// (acc 96 + operands 40 + addressing ~30 > the default 128-VGPR target).
// Staging via global_load_lds width-16: linear LDS dest, inverse-swizzled source.
// EPI 0: qkv scatter (+q scale)   EPI 1: proj + window-reverse+roll + residual -> h_buf f32
// EPI 2: fc1 + poly gelu -> bf16  EPI 3: fc2 + h_buf residual -> f32 out
template<int EPI>
__global__ __launch_bounds__(256, 2) void gemm_bt(const bf16* __restrict__ A,
                                                  const bf16* __restrict__ Bw,
                                                  const float* __restrict__ bias,
                                                  int K, void* __restrict__ outp,
                                                  const float* __restrict__ aux1,
                                                  const float* __restrict__ aux2) {
  __shared__ __align__(16) bf16 Ald[128 * 64];
  __shared__ __align__(16) bf16 Bld[192 * 64];
  const int tid = threadIdx.x;
  const int n0 = blockIdx.x * 192;
  const long m0 = (long)blockIdx.y * 128;
  const int lane = tid & 63, wid = tid >> 6;
  const int wr = (wid >> 1) * 64, wc = (wid & 1) * 96;
  const int lg = lane >> 4, lr = lane & 15;
  const int l3 = lane >> 3, l7 = lane & 7;
  const int chunk = l7 ^ l3;  // involutive source swizzle

  // per-wave staging pointers: A rows wid*32..+32, B rows wid*48..+48 (both ≡0 mod 8)
  const bf16* aptr = A + (m0 + wid * 32 + l3) * (long)K + chunk * 8;
  const bf16* bptr = Bw + (n0 + wid * 48 + l3) * (long)K + chunk * 8;
  char* alds = (char*)Ald + wid * 32 * 128;
  char* blds = (char*)Bld + wid * 48 * 128;
  const long rk8 = 8 * (long)K;

  f32x4 acc[4][6];
  #pragma unroll
  for (int i = 0; i < 4; i++)
    #pragma unroll
    for (int j = 0; j < 6; j++) acc[i][j] = (f32x4){0.f, 0.f, 0.f, 0.f};

  for (int k0 = 0; k0 < K; k0 += 64) {
    GLD16(aptr + k0, alds);
    GLD16(aptr + rk8 + k0, alds + 1024);
    GLD16(aptr + 2 * rk8 + k0, alds + 2048);
    GLD16(aptr + 3 * rk8 + k0, alds + 3072);
    GLD16(bptr + k0, blds);
    GLD16(bptr + rk8 + k0, blds + 1024);
    GLD16(bptr + 2 * rk8 + k0, blds + 2048);
    GLD16(bptr + 3 * rk8 + k0, blds + 3072);
    GLD16(bptr + 4 * rk8 + k0, blds + 4096);
    GLD16(bptr + 5 * rk8 + k0, blds + 5120);
    __syncthreads();
    #pragma unroll
    for (int ks = 0; ks < 2; ks++) {
      bf16x8 af[4], bfr[6];
      #pragma unroll
      for (int i = 0; i < 4; i++) {
        const int row = wr + i * 16 + lr;
        af[i] = *(const bf16x8*)((const char*)Ald + row * 128 + (((ks * 4 + lg) ^ (row & 7)) * 16));
      }
      #pragma unroll
      for (int j = 0; j < 6; j++) {
        const int row = wc + j * 16 + lr;
        bfr[j] = *(const bf16x8*)((const char*)Bld + row * 128 + (((ks * 4 + lg) ^ (row & 7)) * 16));
      }
      #pragma unroll
      for (int i = 0; i < 4; i++)
        #pragma unroll
        for (int j = 0; j < 6; j++)
          acc[i][j] = __builtin_amdgcn_mfma_f32_16x16x32_bf16(af[i], bfr[j], acc[i][j], 0, 0, 0);
    }
    __syncthreads();
  }

  #pragma unroll
  for (int i = 0; i < 4; i++) {
    #pragma unroll
    for (int j = 0; j < 6; j++) {
      #pragma unroll
      for (int r = 0; r < 4; r++) {
        const long m = m0 + wr + i * 16 + lg * 4 + r;   // token row
        const int cn = n0 + wc + j * 16 + lr;           // output col
        float v = acc[i][j][r] + bias[cn];
        if (EPI == 0) {
          const long b_ = m >> 6; const int n = (int)(m & 63);
          const int which = cn / 192, rem = cn - which * 192, head = rem >> 5, d = rem & 31;
          if (which == 0) v *= SCALE_Q;
          ((bf16*)outp)[((b_ * 6 + head) * 3 + which) * 2048 + n * 32 + d] = __float2bfloat16(v);
        } else if (EPI == 1) {
          const long b_ = m >> 6; const int n = (int)(m & 63);
          const int b = (int)(b_ >> 10), wk = (int)(b_ & 1023), wi = wk >> 5, wj = wk & 31;
          const int i_ = n >> 3, j_ = n & 7;
          const int hf = (wi * 8 + i_ + 4) & 255, wf = (wj * 8 + j_ + 4) & 255;
          const long g = (((long)b * 256 + hf) * 256 + wf) * 192 + cn;
          ((float*)outp)[g] = aux1[g] + v;   // h = shortcut + proj(attn)
        } else if (EPI == 2) {
          ((bf16*)outp)[m * 768 + cn] = __float2bfloat16(gelu_f(v));
        } else {
          ((float*)outp)[m * 192 + cn] = aux2[m * 192 + cn] + v;
        }
      }
    }
  }
}

// ---------------- windowed attention: one wave per (window, head) — exact round-1 ----------------
__global__ __launch_bounds__(64) void attn_kernel(const bf16* __restrict__ qkv,
                                                  const float* __restrict__ rpb,
                                                  bf16* __restrict__ outp) {
  __shared__ __align__(16) char smem[14848];
  __shared__ float rps[225];
  const int bid = blockIdx.x;
  const int b_ = bid / 6, head = bid - b_ * 6;
  const int lane = threadIdx.x;
  const long base = ((long)b_ * 6 + head) * 3 * 2048;

  for (int t = lane; t < 225; t += 64) rps[t] = rpb[t * 6 + head];

  #pragma unroll
  for (int q = 0; q < 4; q++) {
    const int f = q * 64 + lane, row = f >> 2, c = f & 3;
    *(uint4*)(smem + row * 80 + c * 16) = *(const uint4*)(qkv + base + row * 32 + c * 8);
    *(uint4*)(smem + 5120 + row * 80 + c * 16) = *(const uint4*)(qkv + base + 2048 + row * 32 + c * 8);
  }
  {  // stage V transposed: Vt[d][m]
    const bf16* vsrc = qkv + base + 4096 + lane * 32;
    bf16 vv[32];
    #pragma unroll
    for (int q = 0; q < 4; q++) *(uint4*)&vv[q * 8] = *(const uint4*)(vsrc + q * 8);
    bf16* vt = (bf16*)(smem + 10240);
    #pragma unroll
    for (int d = 0; d < 32; d++) vt[d * 72 + lane] = vv[d];
  }
  __syncthreads();

  const int lg = lane >> 4, lr = lane & 15;
  const f32x4 z4 = {0.f, 0.f, 0.f, 0.f};
  f32x4 s[4][4];
  {
    bf16x8 a[4], b[4];
    #pragma unroll
    for (int fi = 0; fi < 4; fi++)
      a[fi] = *(const bf16x8*)(smem + (fi * 16 + lr) * 80 + lg * 16);
    #pragma unroll
    for (int fj = 0; fj < 4; fj++)
      b[fj] = *(const bf16x8*)(smem + 5120 + (fj * 16 + lr) * 80 + lg * 16);
    #pragma unroll
    for (int fi = 0; fi < 4; fi++)
      #pragma unroll
      for (int fj = 0; fj < 4; fj++)
        s[fi][fj] = __builtin_amdgcn_mfma_f32_16x16x32_bf16(a[fi], b[fj], z4, 0, 0, 0);
  }

  const int wk = b_ & 1023; const int wi = wk >> 5, wj = wk & 31;
  const bool eh = (wi == 31), ew = (wj == 31);
  bf16* P = (bf16*)smem;
  #pragma unroll
  for (int fi = 0; fi < 4; fi++) {
    #pragma unroll
    for (int r = 0; r < 4; r++) {
      const int n = fi * 16 + lg * 4 + r;
      const int i1 = n >> 3, j1 = n & 7;
      const int labn = (eh ? (i1 < 4 ? 3 : 6) : 0) + (ew ? (j1 < 4 ? 1 : 2) : 0);
      float vals[4];
      #pragma unroll
      for (int fj = 0; fj < 4; fj++) {
        const int m = fj * 16 + lr;
        const int i2 = m >> 3, j2 = m & 7;
        const int labm = (eh ? (i2 < 4 ? 3 : 6) : 0) + (ew ? (j2 < 4 ? 1 : 2) : 0);
        vals[fj] = s[fi][fj][r] + rps[(i1 - i2 + 7) * 15 + (j1 - j2 + 7)]
                 + (labn != labm ? -100.0f : 0.0f);
      }
      float mx = fmaxf(fmaxf(vals[0], vals[1]), fmaxf(vals[2], vals[3]));
      #pragma unroll
      for (int msk = 1; msk < 16; msk <<= 1) mx = fmaxf(mx, __shfl_xor(mx, msk));
      float pe[4]; float sum = 0.f;
      #pragma unroll
      for (int fj = 0; fj < 4; fj++) { pe[fj] = __expf(vals[fj] - mx); sum += pe[fj]; }
      #pragma unroll
      for (int msk = 1; msk < 16; msk <<= 1) sum += __shfl_xor(sum, msk);
      const float rinv = 1.0f / sum;
      #pragma unroll
      for (int fj = 0; fj < 4; fj++)
        P[n * 72 + fj * 16 + lr] = __float2bfloat16(pe[fj] * rinv);
    }
  }
  __syncthreads();

  f32x4 o[4][2];
  #pragma unroll
  for (int fi = 0; fi < 4; fi++)
    #pragma unroll
    for (int fd = 0; fd < 2; fd++) o[fi][fd] = z4;
  const bf16* vt = (const bf16*)(smem + 10240);
  #pragma unroll
  for (int ks = 0; ks < 2; ks++) {
    bf16x8 pa[4], vb[2];
    #pragma unroll
    for (int fi = 0; fi < 4; fi++)
      pa[fi] = *(const bf16x8*)(P + (fi * 16 + lr) * 72 + ks * 32 + lg * 8);
    #pragma unroll
    for (int fd = 0; fd < 2; fd++)
      vb[fd] = *(const bf16x8*)(vt + (fd * 16 + lr) * 72 + ks * 32 + lg * 8);
    #pragma unroll
    for (int fi = 0; fi < 4; fi++)
      #pragma unroll
      for (int fd = 0; fd < 2; fd++)
        o[fi][fd] = __builtin_amdgcn_mfma_f32_16x16x32_bf16(pa[fi], vb[fd], o[fi][fd], 0, 0, 0);
  }
  #pragma unroll
  for (int fi = 0; fi < 4; fi++)
    #pragma unroll
    for (int fd = 0; fd < 2; fd++)
      #pragma unroll
      for (int r = 0; r < 4; r++) {
        const int n = fi * 16 + lg * 4 + r;
        outp[((long)b_ * 64 + n) * 192 + head * 32 + fd * 16 + lr] = __float2bfloat16(o[fi][fd][r]);
      }
}

extern "C" void kernel_launch(void* const* d_in, const int* in_sizes, int n_in,
                              void* d_out, int out_size, void* d_ws, size_t ws_size,
                              hipStream_t stream) {
  const float* x      = (const float*)d_in[0];
  const float* qkv_w  = (const float*)d_in[1];
  const float* qkv_b  = (const float*)d_in[2];
  const float* proj_w = (const float*)d_in[3];
  const float* proj_b = (const float*)d_in[4];
  const float* rpb    = (const float*)d_in[5];
  const float* n1_w   = (const float*)d_in[6];
  const float* n1_b   = (const float*)d_in[7];
  const float* n2_w   = (const float*)d_in[8];
  const float* n2_b   = (const float*)d_in[9];
  const float* fc1_w  = (const float*)d_in[10];
  const float* fc1_b  = (const float*)d_in[11];
  const float* fc2_w  = (const float*)d_in[12];
  const float* fc2_b  = (const float*)d_in[13];

  char* ws = (char*)d_ws;
  // workspace layout — exact round-1/5 proven layout:
  // [0, 884736)             weights bf16
  // [1 MiB, +100663296)     R1: zw -> attn_out -> h_ln  (bf16, M x 192)
  // [101711872, +402653184) R2: qkv (M x 576) -> g (M x 768)  (bf16)
  // [504365056, +201326592) R3: h_buf (M x 192 f32, original token order)
  bf16* qkvw_h  = (bf16*)(ws);
  bf16* projw_h = (bf16*)(ws + 221184);
  bf16* fc1w_h  = (bf16*)(ws + 294912);
  bf16* fc2w_h  = (bf16*)(ws + 589824);
  bf16* r1      = (bf16*)(ws + (1L << 20));
  bf16* r2      = (bf16*)(ws + 101711872L);
  float* hbuf   = (float*)(ws + 504365056L);

  cvt_kernel<<<432, 256, 0, stream>>>(qkv_w, qkvw_h, 110592);
  cvt_kernel<<<144, 256, 0, stream>>>(proj_w, projw_h, 36864);
  cvt_kernel<<<576, 256, 0, stream>>>(fc1_w, fc1w_h, 147456);
  cvt_kernel<<<576, 256, 0, stream>>>(fc2_w, fc2w_h, 147456);

  // LN1 + roll + window partition -> zw (r1)
  ln_kernel<true><<<65536, 256, 0, stream>>>(x, n1_w, n1_b, r1);
  // QKV: zw @ qkv_w^T -> per-(window,head) Q|K|V blocks (r2)
  gemm_bt<0><<<dim3(3, 2048), 256, 0, stream>>>(r1, qkvw_h, qkv_b, 192, r2, nullptr, nullptr);
  // windowed attention -> attn_out (r1)
  attn_kernel<<<24576, 64, 0, stream>>>(r2, rpb, r1);
  // proj + window-reverse + roll + residual -> h_buf (r3, original order)
  gemm_bt<1><<<dim3(1, 2048), 256, 0, stream>>>(r1, projw_h, proj_b, 192, hbuf, x, nullptr);
  // LN2 -> h_ln (r1)
  ln_kernel<false><<<65536, 256, 0, stream>>>(hbuf, n2_w, n2_b, r1);
  // fc1 + gelu -> g (r2)
  gemm_bt<2><<<dim3(4, 2048), 256, 0, stream>>>(r1, fc1w_h, fc1_b, 192, r2, nullptr, nullptr);
  // fc2 + residual -> out (f32)
  gemm_bt<3><<<dim3(1, 2048), 256, 0, stream>>>(r2, fc2w_h, fc2_b, 768, d_out, nullptr, hbuf);
}

// Round 9
// 905.111 us; speedup vs baseline: 1.1600x; 1.0589x over previous
//
#include <hip/hip_runtime.h>
#include <hip/hip_bf16.h>

typedef __attribute__((ext_vector_type(8))) __bf16 bf16x8;
typedef __attribute__((ext_vector_type(4))) float f32x4;
typedef __hip_bfloat16 bf16;

#define SCALE_Q 0.17677669529663687f

// global_load_lds: LDS dest linear (wave-uniform base + lane*16), source pre-swizzled per-lane.
#define LDSP(p) ((__attribute__((address_space(3))) unsigned int*)(unsigned long long)(p))
#define GPTR(p) ((const __attribute__((address_space(1))) unsigned int*)(unsigned long long)(p))
#define GLD16(gp, lp) __builtin_amdgcn_global_load_lds(GPTR(gp), LDSP(lp), 16, 0, 0)

// exact-grade GELU: Abramowitz-Stegun 7.1.26 erf (|err| < 1.5e-7)
__device__ inline float gelu_f(float x) {
  const float ax = fabsf(x) * 0.70710678118654752f;
  const float t = __builtin_amdgcn_rcpf(__builtin_fmaf(0.3275911f, ax, 1.0f));
  const float poly = t * __builtin_fmaf(t, __builtin_fmaf(t, __builtin_fmaf(t,
                     __builtin_fmaf(t, 1.061405429f, -1.453152027f),
                     1.421413741f), -0.284496736f), 0.254829592f);
  const float er = __builtin_fmaf(-poly, __expf(-ax * ax), 1.0f);
  return 0.5f * x * (1.0f + copysignf(er, x));
}

// ---------------- weight fp32 -> bf16 ----------------
__global__ void cvt_kernel(const float* __restrict__ in, bf16* __restrict__ out, int n) {
  int i = blockIdx.x * 256 + threadIdx.x;
  if (i < n) out[i] = __float2bfloat16(in[i]);
}

// ---- LayerNorm (optionally fused shifted-window gather), fp32 in -> bf16 out ----
template<bool GATHER>
__global__ __launch_bounds__(256) void ln_kernel(const float* __restrict__ in,
                                                 const float* __restrict__ gw,
                                                 const float* __restrict__ gb,
                                                 bf16* __restrict__ out) {
  const int t = blockIdx.x * 4 + (threadIdx.x >> 6);
  const int lane = threadIdx.x & 63;
  long g;
  if (GATHER) {
    const int b_ = t >> 6, n = t & 63;
    const int b = b_ >> 10, wk = b_ & 1023, wi = wk >> 5, wj = wk & 31;
    const int i_ = n >> 3, j_ = n & 7;
    const int hf = (wi * 8 + i_ + 4) & 255, wf = (wj * 8 + j_ + 4) & 255;
    g = (((long)b * 256 + hf) * 256 + wf) * 192;
  } else {
    g = (long)t * 192;
  }
  const float x0 = in[g + lane], x1 = in[g + 64 + lane], x2 = in[g + 128 + lane];
  float s = x0 + x1 + x2;
  float s2 = x0 * x0 + x1 * x1 + x2 * x2;
  #pragma unroll
  for (int m = 1; m < 64; m <<= 1) { s += __shfl_xor(s, m); s2 += __shfl_xor(s2, m); }
  const float mu = s * (1.0f / 192.0f);
  const float rstd = rsqrtf(s2 * (1.0f / 192.0f) - mu * mu + 1e-5f);
  const long o = (long)t * 192;
  out[o + lane]       = __float2bfloat16((x0 - mu) * rstd * gw[lane]       + gb[lane]);
  out[o + 64 + lane]  = __float2bfloat16((x1 - mu) * rstd * gw[lane + 64]  + gb[lane + 64]);
  out[o + 128 + lane] = __float2bfloat16((x2 - mu) * rstd * gw[lane + 128] + gb[lane + 128]);
}

// ---------------- GEMM: C[m][n] = sum_k A[m][k] * W[n][k] (+bias), bf16 MFMA ----------------
// BM=128 BN=192 BK=64, 512 threads (8 waves, 4x2 grid, wave tile 32x96).
// acc[2][6]=48 VGPR/thread; __launch_bounds__(512,4) -> <=128 regs, 16 waves/CU, no spill.
// Staging via global_load_lds width-16: linear LDS dest, inverse-swizzled source; LDS image
// bit-identical to the proven layout (slot s of row R holds chunk s^(R&7)).
// EPI 0: qkv scatter (+q scale)   EPI 1: proj + window-reverse+roll + residual -> h_buf f32
// EPI 2: fc1 + poly gelu -> bf16  EPI 3: fc2 + h_buf residual -> f32 out
template<int EPI>
__global__ __launch_bounds__(512, 4) void gemm_bt(const bf16* __restrict__ A,
                                                  const bf16* __restrict__ Bw,
                                                  const float* __restrict__ bias,
                                                  int K, void* __restrict__ outp,
                                                  const float* __restrict__ aux1,
                                                  const float* __restrict__ aux2) {
  __shared__ __align__(16) bf16 Ald[128 * 64];
  __shared__ __align__(16) bf16 Bld[192 * 64];
  const int tid = threadIdx.x;
  const int n0 = blockIdx.x * 192;
  const long m0 = (long)blockIdx.y * 128;
  const int lane = tid & 63, wid = tid >> 6;
  const int wr = (wid >> 1) * 32, wc = (wid & 1) * 96;
  const int lg = lane >> 4, lr = lane & 15;
  const int l3 = lane >> 3, l7 = lane & 7;
  const int chunk = l7 ^ l3;  // involutive source swizzle

  // per-wave staging: A rows wid*16..+16 (2 GLD16), B rows wid*24..+24 (3 GLD16)
  const bf16* aptr = A + (m0 + wid * 16 + l3) * (long)K + chunk * 8;
  const bf16* bptr = Bw + (n0 + wid * 24 + l3) * (long)K + chunk * 8;
  char* alds = (char*)Ald + wid * 16 * 128;
  char* blds = (char*)Bld + wid * 24 * 128;
  const long rk8 = 8 * (long)K;

  f32x4 acc[2][6];
  #pragma unroll
  for (int i = 0; i < 2; i++)
    #pragma unroll
    for (int j = 0; j < 6; j++) acc[i][j] = (f32x4){0.f, 0.f, 0.f, 0.f};

  for (int k0 = 0; k0 < K; k0 += 64) {
    GLD16(aptr + k0, alds);
    GLD16(aptr + rk8 + k0, alds + 1024);
    GLD16(bptr + k0, blds);
    GLD16(bptr + rk8 + k0, blds + 1024);
    GLD16(bptr + 2 * rk8 + k0, blds + 2048);
    __syncthreads();
    #pragma unroll
    for (int ks = 0; ks < 2; ks++) {
      bf16x8 af[2], bfr[6];
      #pragma unroll
      for (int i = 0; i < 2; i++) {
        const int row = wr + i * 16 + lr;
        af[i] = *(const bf16x8*)((const char*)Ald + row * 128 + (((ks * 4 + lg) ^ (row & 7)) * 16));
      }
      #pragma unroll
      for (int j = 0; j < 6; j++) {
        const int row = wc + j * 16 + lr;
        bfr[j] = *(const bf16x8*)((const char*)Bld + row * 128 + (((ks * 4 + lg) ^ (row & 7)) * 16));
      }
      #pragma unroll
      for (int i = 0; i < 2; i++)
        #pragma unroll
        for (int j = 0; j < 6; j++)
          acc[i][j] = __builtin_amdgcn_mfma_f32_16x16x32_bf16(af[i], bfr[j], acc[i][j], 0, 0, 0);
    }
    __syncthreads();
  }

  #pragma unroll
  for (int i = 0; i < 2; i++) {
    #pragma unroll
    for (int j = 0; j < 6; j++) {
      #pragma unroll
      for (int r = 0; r < 4; r++) {
        const long m = m0 + wr + i * 16 + lg * 4 + r;   // token row
        const int cn = n0 + wc + j * 16 + lr;           // output col
        float v = acc[i][j][r] + bias[cn];
        if (EPI == 0) {
          const long b_ = m >> 6; const int n = (int)(m & 63);
          const int which = cn / 192, rem = cn - which * 192, head = rem >> 5, d = rem & 31;
          if (which == 0) v *= SCALE_Q;
          ((bf16*)outp)[((b_ * 6 + head) * 3 + which) * 2048 + n * 32 + d] = __float2bfloat16(v);
        } else if (EPI == 1) {
          const long b_ = m >> 6; const int n = (int)(m & 63);
          const int b = (int)(b_ >> 10), wk = (int)(b_ & 1023), wi = wk >> 5, wj = wk & 31;
          const int i_ = n >> 3, j_ = n & 7;
          const int hf = (wi * 8 + i_ + 4) & 255, wf = (wj * 8 + j_ + 4) & 255;
          const long g = (((long)b * 256 + hf) * 256 + wf) * 192 + cn;
          ((float*)outp)[g] = aux1[g] + v;   // h = shortcut + proj(attn)
        } else if (EPI == 2) {
          ((bf16*)outp)[m * 768 + cn] = __float2bfloat16(gelu_f(v));
        } else {
          ((float*)outp)[m * 192 + cn] = aux2[m * 192 + cn] + v;
        }
      }
    }
  }
}

// ---------------- windowed attention: one wave per (window, head) — exact round-1 ----------------
__global__ __launch_bounds__(64) void attn_kernel(const bf16* __restrict__ qkv,
                                                  const float* __restrict__ rpb,
                                                  bf16* __restrict__ outp) {
  __shared__ __align__(16) char smem[14848];
  __shared__ float rps[225];
  const int bid = blockIdx.x;
  const int b_ = bid / 6, head = bid - b_ * 6;
  const int lane = threadIdx.x;
  const long base = ((long)b_ * 6 + head) * 3 * 2048;

  for (int t = lane; t < 225; t += 64) rps[t] = rpb[t * 6 + head];

  #pragma unroll
  for (int q = 0; q < 4; q++) {
    const int f = q * 64 + lane, row = f >> 2, c = f & 3;
    *(uint4*)(smem + row * 80 + c * 16) = *(const uint4*)(qkv + base + row * 32 + c * 8);
    *(uint4*)(smem + 5120 + row * 80 + c * 16) = *(const uint4*)(qkv + base + 2048 + row * 32 + c * 8);
  }
  {  // stage V transposed: Vt[d][m]
    const bf16* vsrc = qkv + base + 4096 + lane * 32;
    bf16 vv[32];
    #pragma unroll
    for (int q = 0; q < 4; q++) *(uint4*)&vv[q * 8] = *(const uint4*)(vsrc + q * 8);
    bf16* vt = (bf16*)(smem + 10240);
    #pragma unroll
    for (int d = 0; d < 32; d++) vt[d * 72 + lane] = vv[d];
  }
  __syncthreads();

  const int lg = lane >> 4, lr = lane & 15;
  const f32x4 z4 = {0.f, 0.f, 0.f, 0.f};
  f32x4 s[4][4];
  {
    bf16x8 a[4], b[4];
    #pragma unroll
    for (int fi = 0; fi < 4; fi++)
      a[fi] = *(const bf16x8*)(smem + (fi * 16 + lr) * 80 + lg * 16);
    #pragma unroll
    for (int fj = 0; fj < 4; fj++)
      b[fj] = *(const bf16x8*)(smem + 5120 + (fj * 16 + lr) * 80 + lg * 16);
    #pragma unroll
    for (int fi = 0; fi < 4; fi++)
      #pragma unroll
      for (int fj = 0; fj < 4; fj++)
        s[fi][fj] = __builtin_amdgcn_mfma_f32_16x16x32_bf16(a[fi], b[fj], z4, 0, 0, 0);
  }

  const int wk = b_ & 1023; const int wi = wk >> 5, wj = wk & 31;
  const bool eh = (wi == 31), ew = (wj == 31);
  bf16* P = (bf16*)smem;
  #pragma unroll
  for (int fi = 0; fi < 4; fi++) {
    #pragma unroll
    for (int r = 0; r < 4; r++) {
      const int n = fi * 16 + lg * 4 + r;
      const int i1 = n >> 3, j1 = n & 7;
      const int labn = (eh ? (i1 < 4 ? 3 : 6) : 0) + (ew ? (j1 < 4 ? 1 : 2) : 0);
      float vals[4];
      #pragma unroll
      for (int fj = 0; fj < 4; fj++) {
        const int m = fj * 16 + lr;
        const int i2 = m >> 3, j2 = m & 7;
        const int labm = (eh ? (i2 < 4 ? 3 : 6) : 0) + (ew ? (j2 < 4 ? 1 : 2) : 0);
        vals[fj] = s[fi][fj][r] + rps[(i1 - i2 + 7) * 15 + (j1 - j2 + 7)]
                 + (labn != labm ? -100.0f : 0.0f);
      }
      float mx = fmaxf(fmaxf(vals[0], vals[1]), fmaxf(vals[2], vals[3]));
      #pragma unroll
      for (int msk = 1; msk < 16; msk <<= 1) mx = fmaxf(mx, __shfl_xor(mx, msk));
      float pe[4]; float sum = 0.f;
      #pragma unroll
      for (int fj = 0; fj < 4; fj++) { pe[fj] = __expf(vals[fj] - mx); sum += pe[fj]; }
      #pragma unroll
      for (int msk = 1; msk < 16; msk <<= 1) sum += __shfl_xor(sum, msk);
      const float rinv = 1.0f / sum;
      #pragma unroll
      for (int fj = 0; fj < 4; fj++)
        P[n * 72 + fj * 16 + lr] = __float2bfloat16(pe[fj] * rinv);
    }
  }
  __syncthreads();

  f32x4 o[4][2];
  #pragma unroll
  for (int fi = 0; fi < 4; fi++)
    #pragma unroll
    for (int fd = 0; fd < 2; fd++) o[fi][fd] = z4;
  const bf16* vt = (const bf16*)(smem + 10240);
  #pragma unroll
  for (int ks = 0; ks < 2; ks++) {
    bf16x8 pa[4], vb[2];
    #pragma unroll
    for (int fi = 0; fi < 4; fi++)
      pa[fi] = *(const bf16x8*)(P + (fi * 16 + lr) * 72 + ks * 32 + lg * 8);
    #pragma unroll
    for (int fd = 0; fd < 2; fd++)
      vb[fd] = *(const bf16x8*)(vt + (fd * 16 + lr) * 72 + ks * 32 + lg * 8);
    #pragma unroll
    for (int fi = 0; fi < 4; fi++)
      #pragma unroll
      for (int fd = 0; fd < 2; fd++)
        o[fi][fd] = __builtin_amdgcn_mfma_f32_16x16x32_bf16(pa[fi], vb[fd], o[fi][fd], 0, 0, 0);
  }
  #pragma unroll
  for (int fi = 0; fi < 4; fi++)
    #pragma unroll
    for (int fd = 0; fd < 2; fd++)
      #pragma unroll
      for (int r = 0; r < 4; r++) {
        const int n = fi * 16 + lg * 4 + r;
        outp[((long)b_ * 64 + n) * 192 + head * 32 + fd * 16 + lr] = __float2bfloat16(o[fi][fd][r]);
      }
}

extern "C" void kernel_launch(void* const* d_in, const int* in_sizes, int n_in,
                              void* d_out, int out_size, void* d_ws, size_t ws_size,
                              hipStream_t stream) {
  const float* x      = (const float*)d_in[0];
  const float* qkv_w  = (const float*)d_in[1];
  const float* qkv_b  = (const float*)d_in[2];
  const float* proj_w = (const float*)d_in[3];
  const float* proj_b = (const float*)d_in[4];
  const float* rpb    = (const float*)d_in[5];
  const float* n1_w   = (const float*)d_in[6];
  const float* n1_b   = (const float*)d_in[7];
  const float* n2_w   = (const float*)d_in[8];
  const float* n2_b   = (const float*)d_in[9];
  const float* fc1_w  = (const float*)d_in[10];
  const float* fc1_b  = (const float*)d_in[11];
  const float* fc2_w  = (const float*)d_in[12];
  const float* fc2_b  = (const float*)d_in[13];

  char* ws = (char*)d_ws;
  // workspace layout — exact round-1/5 proven layout:
  // [0, 884736)             weights bf16
  // [1 MiB, +100663296)     R1: zw -> attn_out -> h_ln  (bf16, M x 192)
  // [101711872, +402653184) R2: qkv (M x 576) -> g (M x 768)  (bf16)
  // [504365056, +201326592) R3: h_buf (M x 192 f32, original token order)
  bf16* qkvw_h  = (bf16*)(ws);
  bf16* projw_h = (bf16*)(ws + 221184);
  bf16* fc1w_h  = (bf16*)(ws + 294912);
  bf16* fc2w_h  = (bf16*)(ws + 589824);
  bf16* r1      = (bf16*)(ws + (1L << 20));
  bf16* r2      = (bf16*)(ws + 101711872L);
  float* hbuf   = (float*)(ws + 504365056L);

  cvt_kernel<<<432, 256, 0, stream>>>(qkv_w, qkvw_h, 110592);
  cvt_kernel<<<144, 256, 0, stream>>>(proj_w, projw_h, 36864);
  cvt_kernel<<<576, 256, 0, stream>>>(fc1_w, fc1w_h, 147456);
  cvt_kernel<<<576, 256, 0, stream>>>(fc2_w, fc2w_h, 147456);

  // LN1 + roll + window partition -> zw (r1)
  ln_kernel<true><<<65536, 256, 0, stream>>>(x, n1_w, n1_b, r1);
  // QKV: zw @ qkv_w^T -> per-(window,head) Q|K|V blocks (r2)
  gemm_bt<0><<<dim3(3, 2048), 512, 0, stream>>>(r1, qkvw_h, qkv_b, 192, r2, nullptr, nullptr);
  // windowed attention -> attn_out (r1)
  attn_kernel<<<24576, 64, 0, stream>>>(r2, rpb, r1);
  // proj + window-reverse + roll + residual -> h_buf (r3, original order)
  gemm_bt<1><<<dim3(1, 2048), 512, 0, stream>>>(r1, projw_h, proj_b, 192, hbuf, x, nullptr);
  // LN2 -> h_ln (r1)
  ln_kernel<false><<<65536, 256, 0, stream>>>(hbuf, n2_w, n2_b, r1);
  // fc1 + gelu -> g (r2)
  gemm_bt<2><<<dim3(4, 2048), 512, 0, stream>>>(r1, fc1w_h, fc1_b, 192, r2, nullptr, nullptr);
  // fc2 + residual -> out (f32)
  gemm_bt<3><<<dim3(1, 2048), 512, 0, stream>>>(r2, fc2w_h, fc2_b, 768, d_out, nullptr, hbuf);
}